// Round 15
// baseline (897.642 us; speedup 1.0000x reference)
//
#include <hip/hip_runtime.h>
#include <math.h>

// ---------------- problem constants ----------------
constexpr int kB = 4, kT = 6, kN = 512, kC = 8;
constexpr int kH = 64, kF = 16, kE = 32;
constexpr int kKS = 3, kKC = 2, kHOR = 3;
constexpr int kBT = kB * kT;          // 24
constexpr int kRK = kBT * kH;         // 1536
constexpr int L_ENC = 1 + kH + kF;    // 81
constexpr int L_DEC = kH + kH + kF;   // 144
constexpr int PL_ENC = 96;            // enc XH: [Ht(0:64)|Xt(64)|pad(65:80)|feat(80:96)]
constexpr int PL_DEC = 160;           // dec XH: [Hd(0:64)|rHd(64:128)|feat(128:144)|pad]
constexpr int KP_ENC = 3 * PL_ENC;    // 288
constexpr int KP_DGF = 288;           // dec gates folded
constexpr int KP_DEC = 3 * PL_DEC;    // 480 (dec cand)
constexpr float kALPHA = 3.0f;

typedef unsigned short ushortT;
typedef short short8 __attribute__((ext_vector_type(8)));
typedef float f32x4 __attribute__((ext_vector_type(4)));

__device__ __forceinline__ float sigm(float x) { return 1.0f / (1.0f + __expf(-x)); }

__device__ __forceinline__ ushortT f2bf(float f) {
    union { float f; unsigned int u; } v; v.f = f;
    unsigned int r = v.u + 0x7fffu + ((v.u >> 16) & 1u);
    return (ushortT)(r >> 16);
}

__device__ __forceinline__ void fma44(const float4& a, const float4& b, float acc[4][4]) {
    acc[0][0] += a.x*b.x; acc[0][1] += a.x*b.y; acc[0][2] += a.x*b.z; acc[0][3] += a.x*b.w;
    acc[1][0] += a.y*b.x; acc[1][1] += a.y*b.y; acc[1][2] += a.y*b.z; acc[1][3] += a.y*b.w;
    acc[2][0] += a.z*b.x; acc[2][1] += a.z*b.y; acc[2][2] += a.z*b.z; acc[2][3] += a.z*b.w;
    acc[3][0] += a.w*b.x; acc[3][1] += a.w*b.y; acc[3][2] += a.w*b.z; acc[3][3] += a.w*b.w;
}

// ---------------- k_front: prep_all + uvproj_s/nfa + uvproj_c + build_init ----------------
__global__ __launch_bounds__(256) void k_front(
    const float* __restrict__ egW, const float* __restrict__ ecW,
    const float* __restrict__ dgW, const float* __restrict__ dcW,
    const float* __restrict__ w2,
    const float* __restrict__ X, const float* __restrict__ Wu, const float* __restrict__ Wv,
    const float* __restrict__ As, const float* __restrict__ WuC, const float* __restrict__ WvC,
    const float* __restrict__ featr,
    ushortT* __restrict__ WTg_e, ushortT* __restrict__ WTc_e,
    ushortT* __restrict__ WTg_d, ushortT* __restrict__ WTc_d,
    float* __restrict__ w2tK, float* __restrict__ w2tV,
    float* __restrict__ Upr, float* __restrict__ Vpr, float* __restrict__ nf,
    float* __restrict__ Uc, float* __restrict__ Vc,
    ushortT* __restrict__ XHe, ushortT* __restrict__ XHd, float* __restrict__ Ht)
{
    __shared__ float shmem[12288];
    int blk = blockIdx.x, tid = threadIdx.x;
    if (blk < 1472) {
        int idx = blk * 256 + tid;
        if (idx < 73728) {
            int qp = idx % KP_ENC, o = idx / KP_ENC;
            int kk = qp / PL_ENC, l = qp - kk * PL_ENC;
            int lo = (l < 64) ? l + 1 : (l == 64) ? 0 : (l < 80) ? L_ENC : (l - 15);
            int j = o / 128, oo = o - j * 128;
            float v = (lo < L_ENC) ? egW[(size_t)((kk*2 + j)*L_ENC + lo) * 128 + oo] : 0.f;
            WTg_e[idx] = f2bf(v);
        } else if (idx < 110592) {
            int r = idx - 73728;
            int qp = r % KP_ENC, o = r / KP_ENC;
            int kk = qp / PL_ENC, l = qp - kk * PL_ENC;
            int lo = (l < 64) ? l + 1 : (l == 64) ? 0 : (l < 80) ? L_ENC : (l - 15);
            int j = o / 64, oo = o - j * 64;
            float v = (lo < L_ENC) ? ecW[(size_t)((kk*2 + j)*L_ENC + lo) * 64 + oo] : 0.f;
            WTc_e[r] = f2bf(v);
        } else if (idx < 184320) {
            int r = idx - 110592;
            int qp = r % KP_DGF, o = r / KP_DGF;
            int k = qp / 96, p = qp - k * 96;
            int j = o >> 7, oo = o & 127;
            int base = (k*2 + j) * L_DEC;
            float v;
            if (p < 64)      v = dgW[(size_t)(base + p)*128 + oo] + dgW[(size_t)(base + 64 + p)*128 + oo];
            else if (p < 80) v = dgW[(size_t)(base + 128 + (p - 64))*128 + oo];
            else             v = 0.f;
            WTg_d[r] = f2bf(v);
        } else if (idx < 245760) {
            int r = idx - 184320;
            int qp = r % KP_DEC, o = r / KP_DEC;
            int kk = qp / PL_DEC, l = qp - kk * PL_DEC;
            int j = o / 64, oo = o - j * 64;
            float v = (l < L_DEC) ? dcW[(size_t)((kk*2 + j)*L_DEC + l) * 64 + oo] : 0.f;
            WTc_d[r] = f2bf(v);
        } else if (idx < 376832) {
            int r = idx - 245760;
            int kk = r & 511, n = r >> 9;
            int j = kk >> 8, k = kk & 255;
            w2tK[r] = w2[(size_t)(0 + j)*65536 + k*256 + n];
            w2tV[r] = w2[(size_t)(2 + j)*65536 + k*256 + n];
        }
    } else if (blk < 5056) {
        int b2 = blk - 1472;
        if (b2 >= 3072) {
            int i = b2 - 3072;
            float* sa = shmem;
            float a = 0.f;
            for (int j = tid; j < kN; j += 256) a += As[(size_t)i*kN + j];
            sa[tid] = a; __syncthreads();
            for (int s = 128; s > 0; s >>= 1) { if (tid < s) sa[tid] += sa[tid+s]; __syncthreads(); }
            if (!tid) { nf[i*2] = sa[0]; nf[i*2+1] = 1.0f; }
            return;
        }
        int idx = b2 * 256 + tid;
        int h = idx % kH; int bt = (idx / kH) % kBT; int n = idx / (kH * kBT);
        const float* xr = X + ((size_t)bt * kN + n) * kC;
        float u = 0.f, v = 0.f;
#pragma unroll
        for (int c = 0; c < kC; ++c) { float x = xr[c]; u += x * Wu[c*kH + h]; v += x * Wv[c*kH + h]; }
        Upr[(size_t)n * kRK + bt * kH + h] = tanhf(kALPHA * u);
        Vpr[(size_t)n * kRK + bt * kH + h] = tanhf(kALPHA * v);
    } else if (blk < 5080) {
        // uvproj_c with LDS-staged weights (latency fix)
        int bt = blk - 5056;
        float* Xs  = shmem;          // 4096
        float* Wus = shmem + 4096;   // 4096
        float* Wvs = shmem + 8192;   // 4096
        for (int i = tid; i < 4096; i += 256) Xs[i] = X[(size_t)bt*4096 + i];
        int c = tid >> 6, h = tid & 63;
        float u0 = 0.f, v0 = 0.f, u1 = 0.f, v1 = 0.f;
        for (int n0 = 0; n0 < 512; n0 += 64) {
            __syncthreads();
            for (int i = tid; i < 4096; i += 256) { Wus[i] = WuC[n0*64 + i]; Wvs[i] = WvC[n0*64 + i]; }
            __syncthreads();
#pragma unroll 8
            for (int nn = 0; nn < 64; ++nn) {
                float wu = Wus[nn*64 + h], wv = Wvs[nn*64 + h];
                float x0 = Xs[(n0+nn)*8 + c], x1 = Xs[(n0+nn)*8 + c + 4];
                u0 += x0*wu; v0 += x0*wv; u1 += x1*wu; v1 += x1*wv;
            }
        }
        Uc[(size_t)bt*512 + c*64 + h]       = tanhf(kALPHA * u0);
        Vc[(size_t)bt*512 + c*64 + h]       = tanhf(kALPHA * v0);
        Uc[(size_t)bt*512 + (c+4)*64 + h]   = tanhf(kALPHA * u1);
        Vc[(size_t)bt*512 + (c+4)*64 + h]   = tanhf(kALPHA * v1);
    } else {
        int idx = (blk - 5080) * 256 + tid;
        if (idx < 1572864) {
            int l = idx % PL_ENC; int r = idx / PL_ENC;
            float v;
            if (l < 64)       v = 0.f;
            else if (l == 64) { int c = r & 7, m = (r >> 3) & 511, b = r >> 12; v = X[(((size_t)b*kT)*kN + m)*kC + c]; }
            else if (l < 80)  v = 0.f;
            else              { int m = (r >> 3) & 511; v = featr[m*kF + (l - 80)]; }
            XHe[idx] = f2bf(v);
        } else if (idx < 2097152) {
            int r2 = idx - 1572864;
            int l2 = r2 & 31; int r = r2 >> 5;
            float v = (l2 < 16) ? featr[((r >> 3) & 511)*kF + l2] : 0.f;
            XHd[(size_t)r*PL_DEC + 128 + l2] = f2bf(v);
        } else if (idx < 3145728) {
            Ht[idx - 2097152] = 0.f;
        }
    }
}

// ---------------- categorical front helper (bank-conflict-padded LDS) ----------------
__device__ __forceinline__ void cat_front2(
    const float* __restrict__ Uc, const float* __restrict__ Vc, const float* __restrict__ Ac,
    float* UVs, float* red, float* McS, float* Pcs, float* rsA, float* Ans, float* Pns)
{
    int tid = threadIdx.x;
    int cd = tid >> 2, kc = tid & 3;
    int c = cd >> 3, d = cd & 7;
    float s = 0.f;
    for (int bt0 = 0; bt0 < kBT; bt0 += 4) {
        __syncthreads();
        for (int i = tid; i < 2048; i += 256) {
            int btL = i >> 9, rest = i & 511;
            int cc = rest >> 6, hh2 = rest & 63;
            int pidx = btL*520 + cc*65 + hh2;
            UVs[pidx]        = Uc[(size_t)bt0*512 + i];
            UVs[2080 + pidx] = Vc[(size_t)bt0*512 + i];
        }
        __syncthreads();
#pragma unroll
        for (int bt = 0; bt < 4; ++bt)
#pragma unroll
            for (int hh = 0; hh < 16; ++hh) {
                int h = kc*16 + hh;
                s += UVs[bt*520 + c*65 + h] * UVs[2080 + bt*520 + d*65 + h];
            }
    }
    red[tid] = s; __syncthreads();
    if (tid < 64) McS[tid] = red[tid*4] + red[tid*4+1] + red[tid*4+2] + red[tid*4+3];
    __syncthreads();
    if (tid < 8) {
        int i = tid;
        float row[8]; float mx = -1e30f;
#pragma unroll
        for (int j = 0; j < 8; ++j) { float v = fmaxf(McS[i*8+j] - McS[j*8+i], 0.f); row[j] = v; mx = fmaxf(mx, v); }
        float s2 = 0.f;
#pragma unroll
        for (int j = 0; j < 8; ++j) { row[j] = __expf(row[j] - mx); s2 += row[j]; }
        float inv = 1.f / s2;
#pragma unroll
        for (int j = 0; j < 8; ++j) Pcs[i*8+j] = row[j] * inv;
        float a = 0.f;
#pragma unroll
        for (int j = 0; j < 8; ++j) a += Ac[i*8+j];
        rsA[i] = a;
    }
    __syncthreads();
    if (tid < 16) {
        int i = tid >> 1, comp = tid & 1;
        float an = 0.f, pn = 0.f;
#pragma unroll
        for (int j = 0; j < 8; ++j) {
            float nfj = comp ? 1.f : rsA[j];
            an += Ac[i*8+j] * nfj; pn += Pcs[i*8+j] * nfj;
        }
        Ans[i*2+comp] = an; Pns[i*2+comp] = pn;
    }
    __syncthreads();
}

// ---------------- k_p2: Ms split-K8 GEMM (512 blocks) + catmlp (16 blocks) ----------------
union P2Smem {
    struct { float sA[32][68]; float sB[32][68]; } g;
    struct { float UVs[4160]; float red[256]; float McS[64]; float Pcs[64]; float rsA[8];
             float Ans[16]; float Pns[16]; float hA[8][260]; float hP[8][260]; } c;
};

__global__ __launch_bounds__(256) void k_p2(
    const float* __restrict__ Upr, const float* __restrict__ Vpr,
    float* __restrict__ part, float* __restrict__ part4,
    const float* __restrict__ Uc, const float* __restrict__ Vc, const float* __restrict__ Ac,
    const float* __restrict__ w1, const float* __restrict__ b1,
    const float* __restrict__ w2C, const float* __restrict__ b2c,
    float* __restrict__ keyval)
{
    __shared__ P2Smem sm;
    int tid = threadIdx.x;
    if (blockIdx.x < 512) {
        int x = blockIdx.x & 7, y = (blockIdx.x >> 3) & 7, z = blockIdx.x >> 6;
        int tx = tid & 15, ty = tid >> 4;
        int j0 = x * 64, i0 = y * 64;
        int kb = z * 192;
        float acc[4][4] = {};
        for (int k0 = kb; k0 < kb + 192; k0 += 32) {
#pragma unroll
            for (int it = 0; it < 2; ++it) {
                int q = tid + it * 256;
                int row = q >> 3, ks = (q & 7) * 4;
                float4 va = *(const float4*)&Upr[(size_t)(i0 + row)*1536 + k0 + ks];
                float4 vb = *(const float4*)&Vpr[(size_t)(j0 + row)*1536 + k0 + ks];
                sm.g.sA[ks+0][row] = va.x; sm.g.sA[ks+1][row] = va.y; sm.g.sA[ks+2][row] = va.z; sm.g.sA[ks+3][row] = va.w;
                sm.g.sB[ks+0][row] = vb.x; sm.g.sB[ks+1][row] = vb.y; sm.g.sB[ks+2][row] = vb.z; sm.g.sB[ks+3][row] = vb.w;
            }
            __syncthreads();
#pragma unroll
            for (int kk = 0; kk < 32; ++kk) {
                float4 a = *(const float4*)&sm.g.sA[kk][ty*4];
                float4 b = *(const float4*)&sm.g.sB[kk][tx*4];
                fma44(a, b, acc);
            }
            __syncthreads();
        }
        float* dst = (z < 4) ? (part + (size_t)z * 262144) : (part4 + (size_t)(z - 4) * 262144);
#pragma unroll
        for (int i = 0; i < 4; ++i)
#pragma unroll
            for (int j = 0; j < 4; ++j)
                dst[(size_t)(i0 + ty*4 + i)*512 + j0 + tx*4 + j] = acc[i][j];
    } else {
        int r = blockIdx.x - 512;
        int kv = r & 1, c0 = (r >> 1) * 32;
        int qa = kv*2, qp = kv*2 + 1;
        cat_front2(Uc, Vc, Ac, sm.c.UVs, sm.c.red, sm.c.McS, sm.c.Pcs, sm.c.rsA, sm.c.Ans, sm.c.Pns);
        for (int e = tid; e < 2048; e += 256) {
            int i = e >> 8, o = e & 255;
            sm.c.hA[i][o] = fmaxf(sm.c.Ans[i*2]*w1[qa*512 + o] + sm.c.Ans[i*2+1]*w1[qa*512 + 256 + o] + b1[qa*256 + o], 0.f);
            sm.c.hP[i][o] = fmaxf(sm.c.Pns[i*2]*w1[qp*512 + o] + sm.c.Pns[i*2+1]*w1[qp*512 + 256 + o] + b1[qp*256 + o], 0.f);
        }
        __syncthreads();
        int i = tid >> 5, ocl = tid & 31, oc = c0 + ocl;
        float s = b2c[qa*256 + oc] + b2c[qp*256 + oc];
        const float* wA = w2C + (size_t)qa*65536 + oc;
        const float* wP = w2C + (size_t)qp*65536 + oc;
#pragma unroll 4
        for (int k = 0; k < 256; ++k) {
            s += sm.c.hA[i][k] * wA[(size_t)k*256] + sm.c.hP[i][k] * wP[(size_t)k*256];
        }
        keyval[(size_t)kv*2048 + i*256 + oc] = s;
    }
}

// ---------------- k_p3: softmax/anpn (512 blocks) + gcfuse (1 block) ----------------
union P3Smem {
    struct { float s0[256]; float s1[256]; float s2[256]; float s3[256]; float s4[256]; } s;
    struct { float UVs[4160]; float red[256]; float McS[64]; float Pcs[64]; float rsA[8];
             float Ans[16]; float Pns[16]; float dotp[256]; } c;
};

__global__ __launch_bounds__(256) void k_p3(
    const float* __restrict__ part, const float* __restrict__ part4,
    const float* __restrict__ A, const float* __restrict__ nf,
    float* __restrict__ P, float* __restrict__ An, float* __restrict__ Pn,
    const float* __restrict__ keyval,
    const float* __restrict__ Uc, const float* __restrict__ Vc, const float* __restrict__ Ac,
    float* __restrict__ GcF)
{
    __shared__ P3Smem sm;
    int tid = threadIdx.x;
    if (blockIdx.x < 512) {
        int i = blockIdx.x;
        auto mval = [&](int r, int c2) -> float {
            size_t id = (size_t)r*kN + c2;
            float s = part[id] + part[262144 + id] + part[524288 + id] + part[786432 + id];
            s += part4[id] + part4[262144 + id] + part4[524288 + id] + part4[786432 + id];
            return s;
        };
        float mx = -1e30f;
        for (int j = tid; j < kN; j += 256)
            mx = fmaxf(mx, fmaxf(mval(i, j) - mval(j, i), 0.f));
        sm.s.s0[tid] = mx; __syncthreads();
        for (int s = 128; s > 0; s >>= 1) { if (tid < s) sm.s.s0[tid] = fmaxf(sm.s.s0[tid], sm.s.s0[tid+s]); __syncthreads(); }
        mx = sm.s.s0[0]; __syncthreads();
        float sum=0, pn0=0, pn1=0, an0=0, an1=0;
        for (int j = tid; j < kN; j += 256) {
            float v = fmaxf(mval(i, j) - mval(j, i), 0.f);
            float e = __expf(v - mx);
            P[(size_t)i*kN + j] = e;
            float n0 = nf[2*j], n1 = nf[2*j+1];
            float a = A[(size_t)i*kN + j];
            sum += e; pn0 += e*n0; pn1 += e*n1; an0 += a*n0; an1 += a*n1;
        }
        sm.s.s0[tid]=sum; sm.s.s1[tid]=pn0; sm.s.s2[tid]=pn1; sm.s.s3[tid]=an0; sm.s.s4[tid]=an1; __syncthreads();
        for (int s = 128; s > 0; s >>= 1) {
            if (tid < s) { sm.s.s0[tid]+=sm.s.s0[tid+s]; sm.s.s1[tid]+=sm.s.s1[tid+s]; sm.s.s2[tid]+=sm.s.s2[tid+s]; sm.s.s3[tid]+=sm.s.s3[tid+s]; sm.s.s4[tid]+=sm.s.s4[tid+s]; }
            __syncthreads();
        }
        float inv = 1.f / sm.s.s0[0];
        if (!tid) { Pn[i*2] = sm.s.s1[0]*inv; Pn[i*2+1] = sm.s.s2[0]*inv; An[i*2] = sm.s.s3[0]; An[i*2+1] = sm.s.s4[0]; }
        __syncthreads();
        for (int j = tid; j < kN; j += 256) P[(size_t)i*kN + j] *= inv;
    } else {
        cat_front2(Uc, Vc, Ac, sm.c.UVs, sm.c.red, sm.c.McS, sm.c.Pcs, sm.c.rsA, sm.c.Ans, sm.c.Pns);
        int cd = tid >> 2, kc = tid & 3;
        int c = cd >> 3, d = cd & 7;
        const float* key = keyval;
        const float* val = keyval + 2048;
        float s = 0.f;
#pragma unroll 4
        for (int k = kc*64; k < kc*64 + 64; k += 4) {
            float4 k4 = *(const float4*)&key[c*256 + k];
            float4 v4 = *(const float4*)&val[d*256 + k];
            s += k4.x*v4.x + k4.y*v4.y + k4.z*v4.z + k4.w*v4.w;
        }
        sm.c.dotp[tid] = s; __syncthreads();
        if (tid < 64) {
            float t = sm.c.dotp[tid*4] + sm.c.dotp[tid*4+1] + sm.c.dotp[tid*4+2] + sm.c.dotp[tid*4+3];
            float a = sigm(t);
            GcF[tid] = a*Ac[tid] + (1.f - a)*sm.c.Pcs[tid];
        }
    }
}

// ---------------- remaining spatial-chain kernels ----------------

__global__ __launch_bounds__(256) void k_mlp1kv(
    const float* __restrict__ An, const float* __restrict__ Pn,
    const float* __restrict__ w1, const float* __restrict__ b1, float* __restrict__ hid)
{
    int idx = blockIdx.x * 256 + threadIdx.x;
    if (idx >= 524288) return;
    int half = idx >> 18;
    int r = idx & 262143;
    int col = r & 511, i = r >> 9;
    int ia = half*2, ip = half*2 + 1;
    float v;
    if (col < 256) {
        const float* w = w1 + (size_t)ia * 512;
        v = An[i*2]*w[col] + An[i*2+1]*w[256 + col] + b1[ia*256 + col];
    } else {
        int o = col - 256;
        const float* w = w1 + (size_t)ip * 512;
        v = Pn[i*2]*w[o] + Pn[i*2+1]*w[256 + o] + b1[ip*256 + o];
    }
    hid[idx] = fmaxf(v, 0.f);
}

__global__ __launch_bounds__(256) void k_gemm_ntsk(
    const float* __restrict__ A, const float* __restrict__ B, float* __restrict__ part,
    int M, int N, int K, int skl)
{
    __shared__ __align__(16) float sA[32][68];
    __shared__ __align__(16) float sB[32][68];
    int tid = threadIdx.x, tx = tid & 15, ty = tid >> 4;
    int j0 = blockIdx.x * 64, i0 = blockIdx.y * 64;
    int kb = blockIdx.z * skl;
    float acc[4][4] = {};
    for (int k0 = kb; k0 < kb + skl; k0 += 32) {
#pragma unroll
        for (int it = 0; it < 2; ++it) {
            int q = tid + it * 256;
            int row = q >> 3, ks = (q & 7) * 4;
            float4 va = *(const float4*)&A[(size_t)(i0 + row)*K + k0 + ks];
            float4 vb = *(const float4*)&B[(size_t)(j0 + row)*K + k0 + ks];
            sA[ks+0][row] = va.x; sA[ks+1][row] = va.y; sA[ks+2][row] = va.z; sA[ks+3][row] = va.w;
            sB[ks+0][row] = vb.x; sB[ks+1][row] = vb.y; sB[ks+2][row] = vb.z; sB[ks+3][row] = vb.w;
        }
        __syncthreads();
#pragma unroll
        for (int kk = 0; kk < 32; ++kk) {
            float4 a = *(const float4*)&sA[kk][ty*4];
            float4 b = *(const float4*)&sB[kk][tx*4];
            fma44(a, b, acc);
        }
        __syncthreads();
    }
    float* dst = part + (size_t)blockIdx.z * M * N;
#pragma unroll
    for (int i = 0; i < 4; ++i)
#pragma unroll
        for (int j = 0; j < 4; ++j)
            dst[(size_t)(i0 + ty*4 + i)*N + j0 + tx*4 + j] = acc[i][j];
}

__global__ __launch_bounds__(256) void k_ntsk_kv2(
    const float* __restrict__ hid, const float* __restrict__ w2t,
    const float* __restrict__ b2, float* __restrict__ keyval)
{
    __shared__ __align__(16) float sA[32][68];
    __shared__ __align__(16) float sB[32][68];
    int tid = threadIdx.x, tx = tid & 15, ty = tid >> 4;
    int z = blockIdx.z;
    const float* A = hid + (size_t)z * 262144;
    const float* B = w2t + (size_t)z * 131072;
    int j0 = blockIdx.x * 64, i0 = blockIdx.y * 64;
    float acc[4][4] = {};
    for (int k0 = 0; k0 < 512; k0 += 32) {
#pragma unroll
        for (int it = 0; it < 2; ++it) {
            int q = tid + it * 256;
            int row = q >> 3, ks = (q & 7) * 4;
            float4 va = *(const float4*)&A[(size_t)(i0 + row)*512 + k0 + ks];
            float4 vb = *(const float4*)&B[(size_t)(j0 + row)*512 + k0 + ks];
            sA[ks+0][row] = va.x; sA[ks+1][row] = va.y; sA[ks+2][row] = va.z; sA[ks+3][row] = va.w;
            sB[ks+0][row] = vb.x; sB[ks+1][row] = vb.y; sB[ks+2][row] = vb.z; sB[ks+3][row] = vb.w;
        }
        __syncthreads();
#pragma unroll
        for (int kk = 0; kk < 32; ++kk) {
            float4 a = *(const float4*)&sA[kk][ty*4];
            float4 b = *(const float4*)&sB[kk][tx*4];
            fma44(a, b, acc);
        }
        __syncthreads();
    }
    float* dst = keyval + (size_t)z * 131072;
#pragma unroll
    for (int i = 0; i < 4; ++i)
#pragma unroll
        for (int j = 0; j < 4; ++j) {
            int col = j0 + tx*4 + j;
            dst[(size_t)(i0 + ty*4 + i)*256 + col] = acc[i][j] + b2[z*512 + col] + b2[z*512 + 256 + col];
        }
}

__global__ void k_fuse_transp(
    const float* __restrict__ part, const float* __restrict__ As,
    const float* __restrict__ Ps, ushortT* __restrict__ Gt)
{
    __shared__ float tile[32][33];
    int bx = blockIdx.x * 32, by = blockIdx.y * 32;
    int x = threadIdx.x, y0 = threadIdx.y;
    for (int yy = y0; yy < 32; yy += 8) {
        size_t id = (size_t)(by + yy)*kN + bx + x;
        float s = part[id] + part[262144 + id];
        float a = sigm(s);
        tile[yy][x] = a*As[id] + (1.f - a)*Ps[id];
    }
    __syncthreads();
    for (int yy = y0; yy < 32; yy += 8) Gt[(size_t)(bx+yy)*kN + by + x] = f2bf(tile[x][yy]);
}

__global__ __launch_bounds__(256) void k_cheby64(
    const ushortT* __restrict__ Gst, ushortT* __restrict__ Gst2)
{
    __shared__ short sA[64][40];
    __shared__ short sB[64][40];
    int tid = threadIdx.x;
    int m0 = blockIdx.y * 64, j0 = blockIdx.x * 64;
    int w = tid >> 6, lane = tid & 63;
    f32x4 acc[4];
#pragma unroll
    for (int i = 0; i < 4; ++i) acc[i] = (f32x4){0.f, 0.f, 0.f, 0.f};
    for (int k0 = 0; k0 < kN; k0 += 32) {
        {
            int row = tid >> 2, lc = (tid & 3) * 8;
            *(short8*)&sA[row][lc] = *(const short8*)(Gst + (size_t)(m0 + row)*kN + k0 + lc);
        }
        {
            int kr = tid & 31, jc = (tid >> 5) * 8;
            short8 v = *(const short8*)(Gst + (size_t)(k0 + kr)*kN + j0 + jc);
#pragma unroll
            for (int i = 0; i < 8; ++i) sB[jc + i][kr] = v[i];
        }
        __syncthreads();
        short8 bf = *(const short8*)&sB[w*16 + (lane & 15)][(lane >> 4) * 8];
#pragma unroll
        for (int mi = 0; mi < 4; ++mi) {
            short8 af = *(const short8*)&sA[mi*16 + (lane & 15)][(lane >> 4) * 8];
            acc[mi] = __builtin_amdgcn_mfma_f32_16x16x32_bf16(af, bf, acc[mi], 0, 0, 0);
        }
        __syncthreads();
    }
#pragma unroll
    for (int mi = 0; mi < 4; ++mi) {
        int row0 = m0 + mi*16 + (lane >> 4)*4;
        int col = j0 + w*16 + (lane & 15);
#pragma unroll
        for (int q = 0; q < 4; ++q) {
            int row = row0 + q;
            Gst2[(size_t)row*kN + col] = f2bf(2.f*acc[mi][q] - (row == col ? 1.f : 0.f));
        }
    }
}

// ---------------- mapped t1 (compile-time map) ----------------
template<int CLP, int PL, int ACTW, int OFF>
__global__ __launch_bounds__(256) void k_t1m(
    const ushortT* __restrict__ Gst, const ushortT* __restrict__ Xin, ushortT* __restrict__ Yout)
{
    __shared__ short sA[128][40];
    __shared__ short sB[128][40];
    int tid = threadIdx.x;
    int ki = blockIdx.z >> 2, b = blockIdx.z & 3;
    const ushortT* A = Gst + (size_t)ki * kN * kN;
    const ushortT* B = Xin + (size_t)b * kN * CLP;
    ushortT* C = Yout + (size_t)(ki*4 + b) * kN * CLP;
    int m0 = blockIdx.y * 128, j0 = blockIdx.x * 128;
    int w = tid >> 6, lane = tid & 63, wr = w >> 1, wc = w & 1;
    int kr = tid & 31, jc = (tid >> 5) * 8;
    int colr0, colr1;
    { int j = j0 + jc;      int cg = j / ACTW; colr0 = cg*PL + OFF + (j - cg*ACTW); }
    { int j = j0 + jc + 64; int cg = j / ACTW; colr1 = cg*PL + OFF + (j - cg*ACTW); }
    f32x4 acc[4][4];
#pragma unroll
    for (int i = 0; i < 4; ++i)
#pragma unroll
        for (int j = 0; j < 4; ++j) acc[i][j] = (f32x4){0.f, 0.f, 0.f, 0.f};

    for (int k0 = 0; k0 < kN; k0 += 32) {
        {
            int row = tid >> 1, lc = (tid & 1) * 16;
            const ushortT* p = A + (size_t)(m0 + row)*kN + k0 + lc;
            *(short8*)&sA[row][lc]     = *(const short8*)p;
            *(short8*)&sA[row][lc + 8] = *(const short8*)(p + 8);
        }
        {
            short8 v0 = *(const short8*)(B + (size_t)(k0 + kr)*CLP + colr0);
            short8 v1 = *(const short8*)(B + (size_t)(k0 + kr)*CLP + colr1);
#pragma unroll
            for (int i = 0; i < 8; ++i) sB[jc + i][kr] = v0[i];
#pragma unroll
            for (int i = 0; i < 8; ++i) sB[jc + 64 + i][kr] = v1[i];
        }
        __syncthreads();
        short8 af[4], bfr[4];
#pragma unroll
        for (int mi = 0; mi < 4; ++mi)
            af[mi] = *(const short8*)&sA[wr*64 + mi*16 + (lane & 15)][(lane >> 4) * 8];
#pragma unroll
        for (int ni = 0; ni < 4; ++ni)
            bfr[ni] = *(const short8*)&sB[wc*64 + ni*16 + (lane & 15)][(lane >> 4) * 8];
#pragma unroll
        for (int mi = 0; mi < 4; ++mi)
#pragma unroll
            for (int ni = 0; ni < 4; ++ni)
                acc[mi][ni] = __builtin_amdgcn_mfma_f32_16x16x32_bf16(af[mi], bfr[ni], acc[mi][ni], 0, 0, 0);
        __syncthreads();
    }
#pragma unroll
    for (int mi = 0; mi < 4; ++mi) {
#pragma unroll
        for (int ni = 0; ni < 4; ++ni) {
            int row = m0 + wr*64 + mi*16 + (lane >> 4) * 4;
            int fj = j0 + wc*64 + ni*16;
            int cg = fj / ACTW;
            int col = cg*PL + OFF + (fj - cg*ACTW) + (lane & 15);
#pragma unroll
            for (int q = 0; q < 4; ++q)
                C[(size_t)(row + q)*CLP + col] = f2bf(acc[mi][ni][q]);
        }
    }
}

// dec gates t1 with optional feat block (blockIdx.x == 4)
__global__ __launch_bounds__(256) void k_t1m_decg(
    const ushortT* __restrict__ Gst, const ushortT* __restrict__ Xin, ushortT* __restrict__ Yout)
{
    constexpr int CLP = 1280, PL = 160;
    __shared__ short sA[128][40];
    __shared__ short sB[128][40];
    int tid = threadIdx.x;
    int ki = blockIdx.z >> 2, b = blockIdx.z & 3;
    const ushortT* A = Gst + (size_t)ki * kN * kN;
    const ushortT* B = Xin + (size_t)b * kN * CLP;
    ushortT* C = Yout + (size_t)(ki*4 + b) * kN * CLP;
    int ACTW, OFF, j0;
    if (blockIdx.x < 4) { ACTW = 64; OFF = 0; j0 = blockIdx.x * 128; }
    else                { ACTW = 16; OFF = 128; j0 = 0; }
    int m0 = blockIdx.y * 128;
    int w = tid >> 6, lane = tid & 63, wr = w >> 1, wc = w & 1;
    int kr = tid & 31, jc = (tid >> 5) * 8;
    int colr0, colr1;
    { int j = j0 + jc;      int cg = j / ACTW; colr0 = cg*PL + OFF + (j - cg*ACTW); }
    { int j = j0 + jc + 64; int cg = j / ACTW; colr1 = cg*PL + OFF + (j - cg*ACTW); }
    f32x4 acc[4][4];
#pragma unroll
    for (int i = 0; i < 4; ++i)
#pragma unroll
        for (int j = 0; j < 4; ++j) acc[i][j] = (f32x4){0.f, 0.f, 0.f, 0.f};

    for (int k0 = 0; k0 < kN; k0 += 32) {
        {
            int row = tid >> 1, lc = (tid & 1) * 16;
            const ushortT* p = A + (size_t)(m0 + row)*kN + k0 + lc;
            *(short8*)&sA[row][lc]     = *(const short8*)p;
            *(short8*)&sA[row][lc + 8] = *(const short8*)(p + 8);
        }
        {
            short8 v0 = *(const short8*)(B + (size_t)(k0 + kr)*CLP + colr0);
            short8 v1 = *(const short8*)(B + (size_t)(k0 + kr)*CLP + colr1);
#pragma unroll
            for (int i = 0; i < 8; ++i) sB[jc + i][kr] = v0[i];
#pragma unroll
            for (int i = 0; i < 8; ++i) sB[jc + 64 + i][kr] = v1[i];
        }
        __syncthreads();
        short8 af[4], bfr[4];
#pragma unroll
        for (int mi = 0; mi < 4; ++mi)
            af[mi] = *(const short8*)&sA[wr*64 + mi*16 + (lane & 15)][(lane >> 4) * 8];
#pragma unroll
        for (int ni = 0; ni < 4; ++ni)
            bfr[ni] = *(const short8*)&sB[wc*64 + ni*16 + (lane & 15)][(lane >> 4) * 8];
#pragma unroll
        for (int mi = 0; mi < 4; ++mi)
#pragma unroll
            for (int ni = 0; ni < 4; ++ni)
                acc[mi][ni] = __builtin_amdgcn_mfma_f32_16x16x32_bf16(af[mi], bfr[ni], acc[mi][ni], 0, 0, 0);
        __syncthreads();
    }
#pragma unroll
    for (int mi = 0; mi < 4; ++mi) {
#pragma unroll
        for (int ni = 0; ni < 4; ++ni) {
            int row = m0 + wr*64 + mi*16 + (lane >> 4) * 4;
            int fj = j0 + wc*64 + ni*16;
            int cg = fj / ACTW;
            int col = cg*PL + OFF + (fj - cg*ACTW) + (lane & 15);
#pragma unroll
            for (int q = 0; q < 4; ++q)
                C[(size_t)(row + q)*CLP + col] = f2bf(acc[mi][ni][q]);
        }
    }
}

// ---------------- gathered-K GEMM (gates/cand) ----------------
template<int PL, int NQ, int MODE, int FN>
__global__ __launch_bounds__(256) void k_gg(
    const ushortT* __restrict__ XH, const ushortT* __restrict__ Yb,
    const ushortT* __restrict__ WT, float* __restrict__ Cout)
{
    constexpr int BN = 32 * FN;
    constexpr int KP = NQ * 32;
    constexpr int Ntot = 64 * FN;
    __shared__ short sA[128][40];
    __shared__ short sB[BN][40];
    int tid = threadIdx.x;
    int r0 = blockIdx.y * 128, j0 = blockIdx.x * BN;
    int b = r0 >> 12, rr = r0 & 4095;
    const ushortT* src0 = XH + (size_t)r0 * PL;
    const ushortT* src1 = Yb + ((size_t)b       * 4096 + rr) * PL;
    const ushortT* src2 = Yb + ((size_t)(4 + b) * 4096 + rr) * PL;
    int w = tid >> 6, lane = tid & 63, wr = w >> 1, wc = w & 1;
    f32x4 acc[4][FN];
#pragma unroll
    for (int i = 0; i < 4; ++i)
#pragma unroll
        for (int j = 0; j < FN; ++j) acc[i][j] = (f32x4){0.f, 0.f, 0.f, 0.f};

    for (int q = 0; q < NQ; ++q) {
        int k, off;
        if (MODE == 0)      { k = q/3; off = (q - k*3)*32; }
        else if (MODE == 1) { k = q/3; int part = q - k*3; off = (part < 2) ? part*32 : 128; }
        else                { k = q/5; off = (q - k*5)*32; }
        const ushortT* Ap = (k == 0) ? src0 : (k == 1) ? src1 : src2;
        {
            int row = tid >> 1, lc = (tid & 1) * 16;
            const ushortT* p = Ap + (size_t)row * PL + off + lc;
            *(short8*)&sA[row][lc]     = *(const short8*)p;
            *(short8*)&sA[row][lc + 8] = *(const short8*)(p + 8);
        }
        if (FN == 4) {
            int col = tid >> 1, seg = (tid & 1) * 16;
            const ushortT* p = WT + (size_t)(j0 + col)*KP + q*32 + seg;
            *(short8*)&sB[col][seg]     = *(const short8*)p;
            *(short8*)&sB[col][seg + 8] = *(const short8*)(p + 8);
        } else {
            int col = tid >> 2, seg = (tid & 3) * 8;
            *(short8*)&sB[col][seg] = *(const short8*)(WT + (size_t)(j0 + col)*KP + q*32 + seg);
        }
        __syncthreads();
        short8 af[4], bfr[FN];
#pragma unroll
        for (int mi = 0; mi < 4; ++mi)
            af[mi] = *(const short8*)&sA[wr*64 + mi*16 + (lane & 15)][(lane >> 4) * 8];
#pragma unroll
        for (int ni = 0; ni < FN; ++ni)
            bfr[ni] = *(const short8*)&sB[wc*16*FN + ni*16 + (lane & 15)][(lane >> 4) * 8];
#pragma unroll
        for (int mi = 0; mi < 4; ++mi)
#pragma unroll
            for (int ni = 0; ni < FN; ++ni)
                acc[mi][ni] = __builtin_amdgcn_mfma_f32_16x16x32_bf16(af[mi], bfr[ni], acc[mi][ni], 0, 0, 0);
        __syncthreads();
    }
#pragma unroll
    for (int mi = 0; mi < 4; ++mi) {
#pragma unroll
        for (int ni = 0; ni < FN; ++ni) {
            int row = r0 + wr*64 + mi*16 + (lane >> 4) * 4;
            int col = j0 + wc*16*FN + ni*16 + (lane & 15);
#pragma unroll
            for (int q = 0; q < 4; ++q)
                Cout[(size_t)(row + q)*Ntot + col] = acc[mi][ni][q];
        }
    }
}

// ---------------- epilogues ----------------

template<int PL, int XOFF>
__global__ __launch_bounds__(256) void k_gates_ep(
    const float* __restrict__ Gg, const float* __restrict__ GcM,
    const float* __restrict__ gb, const float* __restrict__ Ht,
    float* __restrict__ upd, ushortT* __restrict__ XH)
{
    __shared__ float sG[8][256];
    __shared__ float GcS[64];
    int tid = threadIdx.x, bm = blockIdx.x;
    const float* src = Gg + (size_t)bm * 2048;
    for (int i = tid; i < 2048; i += 256) sG[i >> 8][i & 255] = src[i];
    if (tid < 64) GcS[tid] = GcM[tid];
    __syncthreads();
    int d = tid >> 5, o0 = (tid & 31) * 4;
    size_t rb = (size_t)bm * 8 + d;
#pragma unroll
    for (int q = 0; q < 4; ++q) {
        int o = o0 + q;
        float pre = sG[d][o] + gb[o];
#pragma unroll
        for (int c = 0; c < 8; ++c) pre += GcS[c*8 + d] * sG[c][128 + o];
        float g = sigm(pre);
        if (o < kH) upd[rb*kH + o] = g;
        else {
            int h = o - kH;
            XH[rb*PL + XOFF + h] = f2bf(g * Ht[rb*kH + h]);
        }
    }
}

template<int MODE>
__global__ __launch_bounds__(256) void k_cand_ep(
    const float* __restrict__ Gc2, const float* __restrict__ GcM,
    const float* __restrict__ cb, const float* __restrict__ upd,
    float* __restrict__ Ht, ushortT* __restrict__ XHo,
    const float* __restrict__ X, int tnext,
    const float* __restrict__ ow1, const float* __restrict__ ob1,
    const float* __restrict__ ow2, const float* __restrict__ ob2,
    float* __restrict__ out, int hz)
{
    __shared__ float sG[8][128];
    __shared__ float GcS[64];
    __shared__ float Hn[8][65];
    __shared__ float Pp[8][32];
    int tid = threadIdx.x, bm = blockIdx.x;
    const float* src = Gc2 + (size_t)bm * 1024;
    for (int i = tid; i < 1024; i += 256) sG[i >> 7][i & 127] = src[i];
    if (tid < 64) GcS[tid] = GcM[tid];
    __syncthreads();
    int d = tid >> 5, o0 = (tid & 31) * 2;
    size_t rb = (size_t)bm * 8 + d;
#pragma unroll
    for (int jj = 0; jj < 2; ++jj) {
        int o = o0 + jj;
        float pre = sG[d][o] + cb[o];
#pragma unroll
        for (int c = 0; c < 8; ++c) pre += GcS[c*8 + d] * sG[c][64 + o];
        float cv = tanhf(pre);
        float u = upd[rb*kH + o];
        float h0 = Ht[rb*kH + o];
        float hn = (1.f - u)*h0 + u*cv;
        Ht[rb*kH + o] = hn;
        if (MODE >= 2) Hn[d][o] = hn;
        if (MODE == 0)      XHo[rb*PL_ENC + o] = f2bf(hn);
        else if (MODE <= 2) XHo[rb*PL_DEC + o] = f2bf(hn);
    }
    if (MODE == 0) {
        if (tid < 8) {
            int r = bm*8 + tid;
            int c2 = r & 7, m = (r >> 3) & 511, b2 = r >> 12;
            XHo[(size_t)r*PL_ENC + 64] = f2bf(X[(((size_t)b2*kT + tnext)*kN + m)*kC + c2]);
        }
    }
    if (MODE >= 2) {
        __syncthreads();
        int row = tid >> 5, e = tid & 31;
        float s = ob1[e];
#pragma unroll
        for (int k = 0; k < kH; ++k) s += Hn[row][k] * ow1[k*kE + e];
        Pp[row][e] = fmaxf(s, 0.f) * ow2[e];
        __syncthreads();
        if (tid < 8) {
            float v = ob2[0];
#pragma unroll
            for (int e2 = 0; e2 < 32; ++e2) v += Pp[tid][e2];
            int r = bm*8 + tid;
            int c2 = r & 7, m = (r >> 3) & 511, b2 = r >> 12;
            out[((size_t)(b2*kHOR + hz)*kN + m)*kC + c2] = v;
        }
    }
}

// ---------------- host ----------------
extern "C" void kernel_launch(void* const* d_in, const int* in_sizes, int n_in,
                              void* d_out, int out_size, void* d_ws, size_t ws_size,
                              hipStream_t stream)
{
    (void)in_sizes; (void)n_in; (void)out_size; (void)ws_size;
    const float* X      = (const float*)d_in[0];
    const float* As     = (const float*)d_in[1];
    const float* Ac     = (const float*)d_in[2];
    const float* featr  = (const float*)d_in[3];
    const float* WuS    = (const float*)d_in[4];
    const float* WvS    = (const float*)d_in[5];
    const float* WuC    = (const float*)d_in[6];
    const float* WvC    = (const float*)d_in[7];
    const float* mfS_w1 = (const float*)d_in[8];
    const float* mfS_b1 = (const float*)d_in[9];
    const float* mfS_w2 = (const float*)d_in[10];
    const float* mfS_b2 = (const float*)d_in[11];
    const float* mfC_w1 = (const float*)d_in[12];
    const float* mfC_b1 = (const float*)d_in[13];
    const float* mfC_w2 = (const float*)d_in[14];
    const float* mfC_b2 = (const float*)d_in[15];
    const float* enc_gW = (const float*)d_in[16];
    const float* enc_gb = (const float*)d_in[17];
    const float* enc_cW = (const float*)d_in[18];
    const float* enc_cb = (const float*)d_in[19];
    const float* dec_gW = (const float*)d_in[20];
    const float* dec_gb = (const float*)d_in[21];
    const float* dec_cW = (const float*)d_in[22];
    const float* dec_cb = (const float*)d_in[23];
    const float* out_w1 = (const float*)d_in[24];
    const float* out_b1 = (const float*)d_in[25];
    const float* out_w2 = (const float*)d_in[26];
    const float* out_b2 = (const float*)d_in[27];
    float* out = (float*)d_out;
    float* ws = (float*)d_ws;

    // ---- arena (floats) ----
    float* Ht     = ws;                      // 1,048,576
    float* updb   = Ht + 1048576;            // 1,048,576 (phase1: part slices 4..7)
    float* Gg     = updb + 1048576;          // 4,194,304 (GEMM out + phase1 aliases)
    float* Gs_pad = Gg + 4194304;            // 262,144 (phase1: Uc/Vc)
    float* smallf = Gs_pad + 262144;         // 8,192
    float* nfS = smallf;
    float* AnS = nfS + 1024;
    float* PnS = AnS + 1024;
    float* GcF = PnS + 1024;
    float* kvC = GcF + 64;                   // 4096
    ushortT* XHb  = (ushortT*)(smallf + 8192);   // enc XH: 16384*96
    ushortT* Yb   = XHb + 2621440;               // 5,242,880
    ushortT* GstB = Yb + 5242880;                // 524,288 (Gst + Gst2)
    ushortT* WTg_e = GstB + 524288;              // 73,728
    ushortT* WTc_e = WTg_e + 73728;              // 36,864
    ushortT* WTg_d = WTc_e + 36864;              // 73,728 used
    ushortT* WTc_d = WTg_d + 122880;             // 61,440
    ushortT* XHd   = WTc_d + 61440;              // 16384*160
    // phase-1 aliases inside Gg
    float* Upr   = Gg;                       // 786,432
    float* Vpr   = Upr + 786432;             // 786,432
    float* part  = Vpr + 786432;             // 1,048,576 (slices 0..3)
    float* part4 = updb;                     // 1,048,576 (slices 4..7)
    float* Ps    = part + 1048576;           // 262,144
    float* hidKV = Ps + 262144;              // 524,288 (hidK | hidV)
    float* keyval= hidKV + 524288;           // 262,144 (keyS | valS)
    float* w2tKV = keyval + 262144;          // 262,144
    float* Uc    = Gs_pad;                   // 12,288 (phase-1 only)
    float* Vc    = Uc + 12288;               // 12,288

    constexpr int CLP_ENC = kC * PL_ENC;   // 768
    constexpr int CLP_DEC = kC * PL_DEC;   // 1280

    // ---- phase 0: all independent front work in one launch ----
    k_front<<<17368, 256, 0, stream>>>(
        enc_gW, enc_cW, dec_gW, dec_cW, mfS_w2,
        X, WuS, WvS, As, WuC, WvC, featr,
        WTg_e, WTc_e, WTg_d, WTc_d, w2tKV, w2tKV + 131072,
        Upr, Vpr, nfS, Uc, Vc, XHb, XHd, Ht);

    // ---- phase 1 ----
    k_p2<<<528, 256, 0, stream>>>(Upr, Vpr, part, part4, Uc, Vc, Ac,
                                  mfC_w1, mfC_b1, mfC_w2, mfC_b2, kvC);
    k_p3<<<513, 256, 0, stream>>>(part, part4, As, nfS, Ps, AnS, PnS, kvC, Uc, Vc, Ac, GcF);
    k_mlp1kv<<<2048, 256, 0, stream>>>(AnS, PnS, mfS_w1, mfS_b1, hidKV);
    k_ntsk_kv2<<<dim3(4, 8, 2), 256, 0, stream>>>(hidKV, w2tKV, mfS_b2, keyval);
    k_gemm_ntsk<<<dim3(8, 8, 2), 256, 0, stream>>>(keyval, keyval + 131072, part, 512, 512, 256, 128);
    k_fuse_transp<<<dim3(16, 16), dim3(32, 8), 0, stream>>>(part, As, Ps, GstB);
    k_cheby64<<<dim3(8, 8), 256, 0, stream>>>(GstB, GstB + 262144);

    // ---- encoder ----
    for (int t = 0; t < kT; ++t) {
        if (t == 0)
            k_t1m<CLP_ENC, PL_ENC, 96, 0><<<dim3(6, 4, 8), 256, 0, stream>>>(GstB, XHb, Yb);
        else
            k_t1m<CLP_ENC, PL_ENC, 80, 0><<<dim3(5, 4, 8), 256, 0, stream>>>(GstB, XHb, Yb);
        k_gg<PL_ENC, 9, 0, 4><<<dim3(2, 128), 256, 0, stream>>>(XHb, Yb, WTg_e, Gg);
        k_gates_ep<PL_ENC, 0><<<2048, 256, 0, stream>>>(Gg, GcF, enc_gb, Ht, updb, XHb);
        k_t1m<CLP_ENC, PL_ENC, 64, 0><<<dim3(4, 4, 8), 256, 0, stream>>>(GstB, XHb, Yb);
        k_gg<PL_ENC, 9, 0, 2><<<dim3(2, 128), 256, 0, stream>>>(XHb, Yb, WTc_e, Gg);
        if (t < kT - 1)
            k_cand_ep<0><<<2048, 256, 0, stream>>>(Gg, GcF, enc_cb, updb, Ht, XHb, X, t + 1,
                                                   nullptr, nullptr, nullptr, nullptr, nullptr, 0);
        else
            k_cand_ep<1><<<2048, 256, 0, stream>>>(Gg, GcF, enc_cb, updb, Ht, XHd, nullptr, 0,
                                                   nullptr, nullptr, nullptr, nullptr, nullptr, 0);
    }

    // ---- decoder ----
    for (int hz = 0; hz < kHOR; ++hz) {
        if (hz == 0)
            k_t1m_decg<<<dim3(5, 4, 8), 256, 0, stream>>>(GstB, XHd, Yb);  // gates t1 + feat-Y
        else
            k_t1m_decg<<<dim3(4, 4, 8), 256, 0, stream>>>(GstB, XHd, Yb);
        k_gg<PL_DEC, 9, 1, 4><<<dim3(2, 128), 256, 0, stream>>>(XHd, Yb, WTg_d, Gg);
        k_gates_ep<PL_DEC, 64><<<2048, 256, 0, stream>>>(Gg, GcF, dec_gb, Ht, updb, XHd);
        k_t1m<CLP_DEC, PL_DEC, 64, 64><<<dim3(4, 4, 8), 256, 0, stream>>>(GstB, XHd, Yb);
        k_gg<PL_DEC, 15, 2, 2><<<dim3(2, 128), 256, 0, stream>>>(XHd, Yb, WTc_d, Gg);
        if (hz < kHOR - 1)
            k_cand_ep<2><<<2048, 256, 0, stream>>>(Gg, GcF, dec_cb, updb, Ht, XHd, nullptr, 0,
                                                   out_w1, out_b1, out_w2, out_b2, out, hz);
        else
            k_cand_ep<3><<<2048, 256, 0, stream>>>(Gg, GcF, dec_cb, updb, Ht, XHd, nullptr, 0,
                                                   out_w1, out_b1, out_w2, out_b2, out, hz);
    }
}

// Round 16
// 879.779 us; speedup vs baseline: 1.0203x; 1.0203x over previous
//
#include <hip/hip_runtime.h>
#include <math.h>

// ---------------- problem constants ----------------
constexpr int kB = 4, kT = 6, kN = 512, kC = 8;
constexpr int kH = 64, kF = 16, kE = 32;
constexpr int kKS = 3, kKC = 2, kHOR = 3;
constexpr int kBT = kB * kT;          // 24
constexpr int kRK = kBT * kH;         // 1536
constexpr int L_ENC = 1 + kH + kF;    // 81
constexpr int L_DEC = kH + kH + kF;   // 144
constexpr int PL_ENC = 96;            // enc XH: [Ht(0:64)|Xt(64)|pad(65:80)|feat(80:96)]
constexpr int PL_DEC = 160;           // dec XH: [Hd(0:64)|rHd(64:128)|feat(128:144)|pad]
constexpr int KP_ENC = 3 * PL_ENC;    // 288
constexpr int KP_DGF = 288;           // dec gates folded
constexpr int KP_DEC = 3 * PL_DEC;    // 480 (dec cand)
constexpr float kALPHA = 3.0f;

typedef unsigned short ushortT;
typedef short short8 __attribute__((ext_vector_type(8)));
typedef float f32x4 __attribute__((ext_vector_type(4)));

__device__ __forceinline__ float sigm(float x) { return 1.0f / (1.0f + __expf(-x)); }

__device__ __forceinline__ ushortT f2bf(float f) {
    union { float f; unsigned int u; } v; v.f = f;
    unsigned int r = v.u + 0x7fffu + ((v.u >> 16) & 1u);
    return (ushortT)(r >> 16);
}

__device__ __forceinline__ void fma44(const float4& a, const float4& b, float acc[4][4]) {
    acc[0][0] += a.x*b.x; acc[0][1] += a.x*b.y; acc[0][2] += a.x*b.z; acc[0][3] += a.x*b.w;
    acc[1][0] += a.y*b.x; acc[1][1] += a.y*b.y; acc[1][2] += a.y*b.z; acc[1][3] += a.y*b.w;
    acc[2][0] += a.z*b.x; acc[2][1] += a.z*b.y; acc[2][2] += a.z*b.z; acc[2][3] += a.z*b.w;
    acc[3][0] += a.w*b.x; acc[3][1] += a.w*b.y; acc[3][2] += a.w*b.z; acc[3][3] += a.w*b.w;
}

// ---------------- k_front: prep_all + uvproj_s/nfa + uvproj_c + build_init ----------------
__global__ __launch_bounds__(256) void k_front(
    const float* __restrict__ egW, const float* __restrict__ ecW,
    const float* __restrict__ dgW, const float* __restrict__ dcW,
    const float* __restrict__ w2,
    const float* __restrict__ X, const float* __restrict__ Wu, const float* __restrict__ Wv,
    const float* __restrict__ As, const float* __restrict__ WuC, const float* __restrict__ WvC,
    const float* __restrict__ featr,
    ushortT* __restrict__ WTg_e, ushortT* __restrict__ WTc_e,
    ushortT* __restrict__ WTg_d, ushortT* __restrict__ WTc_d,
    float* __restrict__ w2tK, float* __restrict__ w2tV,
    float* __restrict__ Upr, float* __restrict__ Vpr, float* __restrict__ nf,
    float* __restrict__ Uc, float* __restrict__ Vc,
    ushortT* __restrict__ XHe, ushortT* __restrict__ XHd, float* __restrict__ Ht)
{
    __shared__ float shmem[12288];
    int blk = blockIdx.x, tid = threadIdx.x;
    if (blk < 1472) {
        int idx = blk * 256 + tid;
        if (idx < 73728) {
            int qp = idx % KP_ENC, o = idx / KP_ENC;
            int kk = qp / PL_ENC, l = qp - kk * PL_ENC;
            int lo = (l < 64) ? l + 1 : (l == 64) ? 0 : (l < 80) ? L_ENC : (l - 15);
            int j = o / 128, oo = o - j * 128;
            float v = (lo < L_ENC) ? egW[(size_t)((kk*2 + j)*L_ENC + lo) * 128 + oo] : 0.f;
            WTg_e[idx] = f2bf(v);
        } else if (idx < 110592) {
            int r = idx - 73728;
            int qp = r % KP_ENC, o = r / KP_ENC;
            int kk = qp / PL_ENC, l = qp - kk * PL_ENC;
            int lo = (l < 64) ? l + 1 : (l == 64) ? 0 : (l < 80) ? L_ENC : (l - 15);
            int j = o / 64, oo = o - j * 64;
            float v = (lo < L_ENC) ? ecW[(size_t)((kk*2 + j)*L_ENC + lo) * 64 + oo] : 0.f;
            WTc_e[r] = f2bf(v);
        } else if (idx < 184320) {
            int r = idx - 110592;
            int qp = r % KP_DGF, o = r / KP_DGF;
            int k = qp / 96, p = qp - k * 96;
            int j = o >> 7, oo = o & 127;
            int base = (k*2 + j) * L_DEC;
            float v;
            if (p < 64)      v = dgW[(size_t)(base + p)*128 + oo] + dgW[(size_t)(base + 64 + p)*128 + oo];
            else if (p < 80) v = dgW[(size_t)(base + 128 + (p - 64))*128 + oo];
            else             v = 0.f;
            WTg_d[r] = f2bf(v);
        } else if (idx < 245760) {
            int r = idx - 184320;
            int qp = r % KP_DEC, o = r / KP_DEC;
            int kk = qp / PL_DEC, l = qp - kk * PL_DEC;
            int j = o / 64, oo = o - j * 64;
            float v = (l < L_DEC) ? dcW[(size_t)((kk*2 + j)*L_DEC + l) * 64 + oo] : 0.f;
            WTc_d[r] = f2bf(v);
        } else if (idx < 376832) {
            int r = idx - 245760;
            int kk = r & 511, n = r >> 9;
            int j = kk >> 8, k = kk & 255;
            w2tK[r] = w2[(size_t)(0 + j)*65536 + k*256 + n];
            w2tV[r] = w2[(size_t)(2 + j)*65536 + k*256 + n];
        }
    } else if (blk < 5056) {
        int b2 = blk - 1472;
        if (b2 >= 3072) {
            int i = b2 - 3072;
            float* sa = shmem;
            float a = 0.f;
            for (int j = tid; j < kN; j += 256) a += As[(size_t)i*kN + j];
            sa[tid] = a; __syncthreads();
            for (int s = 128; s > 0; s >>= 1) { if (tid < s) sa[tid] += sa[tid+s]; __syncthreads(); }
            if (!tid) { nf[i*2] = sa[0]; nf[i*2+1] = 1.0f; }
            return;
        }
        int idx = b2 * 256 + tid;
        int h = idx % kH; int bt = (idx / kH) % kBT; int n = idx / (kH * kBT);
        const float* xr = X + ((size_t)bt * kN + n) * kC;
        float u = 0.f, v = 0.f;
#pragma unroll
        for (int c = 0; c < kC; ++c) { float x = xr[c]; u += x * Wu[c*kH + h]; v += x * Wv[c*kH + h]; }
        Upr[(size_t)n * kRK + bt * kH + h] = tanhf(kALPHA * u);
        Vpr[(size_t)n * kRK + bt * kH + h] = tanhf(kALPHA * v);
    } else if (blk < 5080) {
        // uvproj_c with LDS-staged weights
        int bt = blk - 5056;
        float* Xs  = shmem;          // 4096
        float* Wus = shmem + 4096;   // 4096
        float* Wvs = shmem + 8192;   // 4096
        for (int i = tid; i < 4096; i += 256) Xs[i] = X[(size_t)bt*4096 + i];
        int c = tid >> 6, h = tid & 63;
        float u0 = 0.f, v0 = 0.f, u1 = 0.f, v1 = 0.f;
        for (int n0 = 0; n0 < 512; n0 += 64) {
            __syncthreads();
            for (int i = tid; i < 4096; i += 256) { Wus[i] = WuC[n0*64 + i]; Wvs[i] = WvC[n0*64 + i]; }
            __syncthreads();
#pragma unroll 8
            for (int nn = 0; nn < 64; ++nn) {
                float wu = Wus[nn*64 + h], wv = Wvs[nn*64 + h];
                float x0 = Xs[(n0+nn)*8 + c], x1 = Xs[(n0+nn)*8 + c + 4];
                u0 += x0*wu; v0 += x0*wv; u1 += x1*wu; v1 += x1*wv;
            }
        }
        Uc[(size_t)bt*512 + c*64 + h]       = tanhf(kALPHA * u0);
        Vc[(size_t)bt*512 + c*64 + h]       = tanhf(kALPHA * v0);
        Uc[(size_t)bt*512 + (c+4)*64 + h]   = tanhf(kALPHA * u1);
        Vc[(size_t)bt*512 + (c+4)*64 + h]   = tanhf(kALPHA * v1);
    } else {
        int idx = (blk - 5080) * 256 + tid;
        if (idx < 1572864) {
            int l = idx % PL_ENC; int r = idx / PL_ENC;
            float v;
            if (l < 64)       v = 0.f;
            else if (l == 64) { int c = r & 7, m = (r >> 3) & 511, b = r >> 12; v = X[(((size_t)b*kT)*kN + m)*kC + c]; }
            else if (l < 80)  v = 0.f;
            else              { int m = (r >> 3) & 511; v = featr[m*kF + (l - 80)]; }
            XHe[idx] = f2bf(v);
        } else if (idx < 2097152) {
            int r2 = idx - 1572864;
            int l2 = r2 & 31; int r = r2 >> 5;
            float v = (l2 < 16) ? featr[((r >> 3) & 511)*kF + l2] : 0.f;
            XHd[(size_t)r*PL_DEC + 128 + l2] = f2bf(v);
        } else if (idx < 3145728) {
            Ht[idx - 2097152] = 0.f;
        }
    }
}

// ---------------- categorical front helper (bank-conflict-padded LDS) ----------------
__device__ __forceinline__ void cat_front2(
    const float* __restrict__ Uc, const float* __restrict__ Vc, const float* __restrict__ Ac,
    float* UVs, float* red, float* McS, float* Pcs, float* rsA, float* Ans, float* Pns)
{
    int tid = threadIdx.x;
    int cd = tid >> 2, kc = tid & 3;
    int c = cd >> 3, d = cd & 7;
    float s = 0.f;
    for (int bt0 = 0; bt0 < kBT; bt0 += 4) {
        __syncthreads();
        for (int i = tid; i < 2048; i += 256) {
            int btL = i >> 9, rest = i & 511;
            int cc = rest >> 6, hh2 = rest & 63;
            int pidx = btL*520 + cc*65 + hh2;
            UVs[pidx]        = Uc[(size_t)bt0*512 + i];
            UVs[2080 + pidx] = Vc[(size_t)bt0*512 + i];
        }
        __syncthreads();
#pragma unroll
        for (int bt = 0; bt < 4; ++bt)
#pragma unroll
            for (int hh = 0; hh < 16; ++hh) {
                int h = kc*16 + hh;
                s += UVs[bt*520 + c*65 + h] * UVs[2080 + bt*520 + d*65 + h];
            }
    }
    red[tid] = s; __syncthreads();
    if (tid < 64) McS[tid] = red[tid*4] + red[tid*4+1] + red[tid*4+2] + red[tid*4+3];
    __syncthreads();
    if (tid < 8) {
        int i = tid;
        float row[8]; float mx = -1e30f;
#pragma unroll
        for (int j = 0; j < 8; ++j) { float v = fmaxf(McS[i*8+j] - McS[j*8+i], 0.f); row[j] = v; mx = fmaxf(mx, v); }
        float s2 = 0.f;
#pragma unroll
        for (int j = 0; j < 8; ++j) { row[j] = __expf(row[j] - mx); s2 += row[j]; }
        float inv = 1.f / s2;
#pragma unroll
        for (int j = 0; j < 8; ++j) Pcs[i*8+j] = row[j] * inv;
        float a = 0.f;
#pragma unroll
        for (int j = 0; j < 8; ++j) a += Ac[i*8+j];
        rsA[i] = a;
    }
    __syncthreads();
    if (tid < 16) {
        int i = tid >> 1, comp = tid & 1;
        float an = 0.f, pn = 0.f;
#pragma unroll
        for (int j = 0; j < 8; ++j) {
            float nfj = comp ? 1.f : rsA[j];
            an += Ac[i*8+j] * nfj; pn += Pcs[i*8+j] * nfj;
        }
        Ans[i*2+comp] = an; Pns[i*2+comp] = pn;
    }
    __syncthreads();
}

// ---------------- k_p2: Ms split-K4 GEMM (256 blocks) + catmlp (16 blocks) ----------------
union P2Smem {
    struct { float sA[32][68]; float sB[32][68]; } g;
    struct { float UVs[4160]; float red[256]; float McS[64]; float Pcs[64]; float rsA[8];
             float Ans[16]; float Pns[16]; float hA[8][260]; float hP[8][260]; } c;
};

__global__ __launch_bounds__(256) void k_p2(
    const float* __restrict__ Upr, const float* __restrict__ Vpr, float* __restrict__ part,
    const float* __restrict__ Uc, const float* __restrict__ Vc, const float* __restrict__ Ac,
    const float* __restrict__ w1, const float* __restrict__ b1,
    const float* __restrict__ w2C, const float* __restrict__ b2c,
    float* __restrict__ keyval)
{
    __shared__ P2Smem sm;
    int tid = threadIdx.x;
    if (blockIdx.x < 256) {
        int x = blockIdx.x & 7, y = (blockIdx.x >> 3) & 7, z = blockIdx.x >> 6;
        int tx = tid & 15, ty = tid >> 4;
        int j0 = x * 64, i0 = y * 64;
        int kb = z * 384;
        float acc[4][4] = {};
        for (int k0 = kb; k0 < kb + 384; k0 += 32) {
#pragma unroll
            for (int it = 0; it < 2; ++it) {
                int q = tid + it * 256;
                int row = q >> 3, ks = (q & 7) * 4;
                float4 va = *(const float4*)&Upr[(size_t)(i0 + row)*1536 + k0 + ks];
                float4 vb = *(const float4*)&Vpr[(size_t)(j0 + row)*1536 + k0 + ks];
                sm.g.sA[ks+0][row] = va.x; sm.g.sA[ks+1][row] = va.y; sm.g.sA[ks+2][row] = va.z; sm.g.sA[ks+3][row] = va.w;
                sm.g.sB[ks+0][row] = vb.x; sm.g.sB[ks+1][row] = vb.y; sm.g.sB[ks+2][row] = vb.z; sm.g.sB[ks+3][row] = vb.w;
            }
            __syncthreads();
#pragma unroll
            for (int kk = 0; kk < 32; ++kk) {
                float4 a = *(const float4*)&sm.g.sA[kk][ty*4];
                float4 b = *(const float4*)&sm.g.sB[kk][tx*4];
                fma44(a, b, acc);
            }
            __syncthreads();
        }
        float* dst = part + (size_t)z * 262144;
#pragma unroll
        for (int i = 0; i < 4; ++i)
#pragma unroll
            for (int j = 0; j < 4; ++j)
                dst[(size_t)(i0 + ty*4 + i)*512 + j0 + tx*4 + j] = acc[i][j];
    } else {
        int r = blockIdx.x - 256;
        int kv = r & 1, c0 = (r >> 1) * 32;
        int qa = kv*2, qp = kv*2 + 1;
        cat_front2(Uc, Vc, Ac, sm.c.UVs, sm.c.red, sm.c.McS, sm.c.Pcs, sm.c.rsA, sm.c.Ans, sm.c.Pns);
        for (int e = tid; e < 2048; e += 256) {
            int i = e >> 8, o = e & 255;
            sm.c.hA[i][o] = fmaxf(sm.c.Ans[i*2]*w1[qa*512 + o] + sm.c.Ans[i*2+1]*w1[qa*512 + 256 + o] + b1[qa*256 + o], 0.f);
            sm.c.hP[i][o] = fmaxf(sm.c.Pns[i*2]*w1[qp*512 + o] + sm.c.Pns[i*2+1]*w1[qp*512 + 256 + o] + b1[qp*256 + o], 0.f);
        }
        __syncthreads();
        int i = tid >> 5, ocl = tid & 31, oc = c0 + ocl;
        float s = b2c[qa*256 + oc] + b2c[qp*256 + oc];
        const float* wA = w2C + (size_t)qa*65536 + oc;
        const float* wP = w2C + (size_t)qp*65536 + oc;
#pragma unroll 4
        for (int k = 0; k < 256; ++k) {
            s += sm.c.hA[i][k] * wA[(size_t)k*256] + sm.c.hP[i][k] * wP[(size_t)k*256];
        }
        keyval[(size_t)kv*2048 + i*256 + oc] = s;
    }
}

// ---------------- k_p3: softmax/anpn (512 blocks) + gcfuse (1 block) ----------------
union P3Smem {
    struct { float s0[256]; float s1[256]; float s2[256]; float s3[256]; float s4[256]; } s;
    struct { float UVs[4160]; float red[256]; float McS[64]; float Pcs[64]; float rsA[8];
             float Ans[16]; float Pns[16]; float dotp[256]; } c;
};

__global__ __launch_bounds__(256) void k_p3(
    const float* __restrict__ part, const float* __restrict__ A, const float* __restrict__ nf,
    float* __restrict__ P, float* __restrict__ An, float* __restrict__ Pn,
    const float* __restrict__ keyval,
    const float* __restrict__ Uc, const float* __restrict__ Vc, const float* __restrict__ Ac,
    float* __restrict__ GcF)
{
    __shared__ P3Smem sm;
    int tid = threadIdx.x;
    if (blockIdx.x < 512) {
        int i = blockIdx.x;
        auto mval = [&](int r, int c2) -> float {
            size_t id = (size_t)r*kN + c2;
            return part[id] + part[262144 + id] + part[524288 + id] + part[786432 + id];
        };
        float mx = -1e30f;
        for (int j = tid; j < kN; j += 256)
            mx = fmaxf(mx, fmaxf(mval(i, j) - mval(j, i), 0.f));
        sm.s.s0[tid] = mx; __syncthreads();
        for (int s = 128; s > 0; s >>= 1) { if (tid < s) sm.s.s0[tid] = fmaxf(sm.s.s0[tid], sm.s.s0[tid+s]); __syncthreads(); }
        mx = sm.s.s0[0]; __syncthreads();
        float sum=0, pn0=0, pn1=0, an0=0, an1=0;
        for (int j = tid; j < kN; j += 256) {
            float v = fmaxf(mval(i, j) - mval(j, i), 0.f);
            float e = __expf(v - mx);
            P[(size_t)i*kN + j] = e;
            float n0 = nf[2*j], n1 = nf[2*j+1];
            float a = A[(size_t)i*kN + j];
            sum += e; pn0 += e*n0; pn1 += e*n1; an0 += a*n0; an1 += a*n1;
        }
        sm.s.s0[tid]=sum; sm.s.s1[tid]=pn0; sm.s.s2[tid]=pn1; sm.s.s3[tid]=an0; sm.s.s4[tid]=an1; __syncthreads();
        for (int s = 128; s > 0; s >>= 1) {
            if (tid < s) { sm.s.s0[tid]+=sm.s.s0[tid+s]; sm.s.s1[tid]+=sm.s.s1[tid+s]; sm.s.s2[tid]+=sm.s.s2[tid+s]; sm.s.s3[tid]+=sm.s.s3[tid+s]; sm.s.s4[tid]+=sm.s.s4[tid+s]; }
            __syncthreads();
        }
        float inv = 1.f / sm.s.s0[0];
        if (!tid) { Pn[i*2] = sm.s.s1[0]*inv; Pn[i*2+1] = sm.s.s2[0]*inv; An[i*2] = sm.s.s3[0]; An[i*2+1] = sm.s.s4[0]; }
        __syncthreads();
        for (int j = tid; j < kN; j += 256) P[(size_t)i*kN + j] *= inv;
    } else {
        cat_front2(Uc, Vc, Ac, sm.c.UVs, sm.c.red, sm.c.McS, sm.c.Pcs, sm.c.rsA, sm.c.Ans, sm.c.Pns);
        int cd = tid >> 2, kc = tid & 3;
        int c = cd >> 3, d = cd & 7;
        const float* key = keyval;
        const float* val = keyval + 2048;
        float s = 0.f;
#pragma unroll 4
        for (int k = kc*64; k < kc*64 + 64; k += 4) {
            float4 k4 = *(const float4*)&key[c*256 + k];
            float4 v4 = *(const float4*)&val[d*256 + k];
            s += k4.x*v4.x + k4.y*v4.y + k4.z*v4.z + k4.w*v4.w;
        }
        sm.c.dotp[tid] = s; __syncthreads();
        if (tid < 64) {
            float t = sm.c.dotp[tid*4] + sm.c.dotp[tid*4+1] + sm.c.dotp[tid*4+2] + sm.c.dotp[tid*4+3];
            float a = sigm(t);
            GcF[tid] = a*Ac[tid] + (1.f - a)*sm.c.Pcs[tid];
        }
    }
}

// ---------------- remaining spatial-chain kernels ----------------

__global__ __launch_bounds__(256) void k_mlp1kv(
    const float* __restrict__ An, const float* __restrict__ Pn,
    const float* __restrict__ w1, const float* __restrict__ b1, float* __restrict__ hid)
{
    int idx = blockIdx.x * 256 + threadIdx.x;
    if (idx >= 524288) return;
    int half = idx >> 18;
    int r = idx & 262143;
    int col = r & 511, i = r >> 9;
    int ia = half*2, ip = half*2 + 1;
    float v;
    if (col < 256) {
        const float* w = w1 + (size_t)ia * 512;
        v = An[i*2]*w[col] + An[i*2+1]*w[256 + col] + b1[ia*256 + col];
    } else {
        int o = col - 256;
        const float* w = w1 + (size_t)ip * 512;
        v = Pn[i*2]*w[o] + Pn[i*2+1]*w[256 + o] + b1[ip*256 + o];
    }
    hid[idx] = fmaxf(v, 0.f);
}

__global__ __launch_bounds__(256) void k_gemm_ntsk(
    const float* __restrict__ A, const float* __restrict__ B, float* __restrict__ part,
    int M, int N, int K, int skl)
{
    __shared__ __align__(16) float sA[32][68];
    __shared__ __align__(16) float sB[32][68];
    int tid = threadIdx.x, tx = tid & 15, ty = tid >> 4;
    int j0 = blockIdx.x * 64, i0 = blockIdx.y * 64;
    int kb = blockIdx.z * skl;
    float acc[4][4] = {};
    for (int k0 = kb; k0 < kb + skl; k0 += 32) {
#pragma unroll
        for (int it = 0; it < 2; ++it) {
            int q = tid + it * 256;
            int row = q >> 3, ks = (q & 7) * 4;
            float4 va = *(const float4*)&A[(size_t)(i0 + row)*K + k0 + ks];
            float4 vb = *(const float4*)&B[(size_t)(j0 + row)*K + k0 + ks];
            sA[ks+0][row] = va.x; sA[ks+1][row] = va.y; sA[ks+2][row] = va.z; sA[ks+3][row] = va.w;
            sB[ks+0][row] = vb.x; sB[ks+1][row] = vb.y; sB[ks+2][row] = vb.z; sB[ks+3][row] = vb.w;
        }
        __syncthreads();
#pragma unroll
        for (int kk = 0; kk < 32; ++kk) {
            float4 a = *(const float4*)&sA[kk][ty*4];
            float4 b = *(const float4*)&sB[kk][tx*4];
            fma44(a, b, acc);
        }
        __syncthreads();
    }
    float* dst = part + (size_t)blockIdx.z * M * N;
#pragma unroll
    for (int i = 0; i < 4; ++i)
#pragma unroll
        for (int j = 0; j < 4; ++j)
            dst[(size_t)(i0 + ty*4 + i)*N + j0 + tx*4 + j] = acc[i][j];
}

__global__ __launch_bounds__(256) void k_ntsk_kv2(
    const float* __restrict__ hid, const float* __restrict__ w2t,
    const float* __restrict__ b2, float* __restrict__ keyval)
{
    __shared__ __align__(16) float sA[32][68];
    __shared__ __align__(16) float sB[32][68];
    int tid = threadIdx.x, tx = tid & 15, ty = tid >> 4;
    int z = blockIdx.z;
    const float* A = hid + (size_t)z * 262144;
    const float* B = w2t + (size_t)z * 131072;
    int j0 = blockIdx.x * 64, i0 = blockIdx.y * 64;
    float acc[4][4] = {};
    for (int k0 = 0; k0 < 512; k0 += 32) {
#pragma unroll
        for (int it = 0; it < 2; ++it) {
            int q = tid + it * 256;
            int row = q >> 3, ks = (q & 7) * 4;
            float4 va = *(const float4*)&A[(size_t)(i0 + row)*512 + k0 + ks];
            float4 vb = *(const float4*)&B[(size_t)(j0 + row)*512 + k0 + ks];
            sA[ks+0][row] = va.x; sA[ks+1][row] = va.y; sA[ks+2][row] = va.z; sA[ks+3][row] = va.w;
            sB[ks+0][row] = vb.x; sB[ks+1][row] = vb.y; sB[ks+2][row] = vb.z; sB[ks+3][row] = vb.w;
        }
        __syncthreads();
#pragma unroll
        for (int kk = 0; kk < 32; ++kk) {
            float4 a = *(const float4*)&sA[kk][ty*4];
            float4 b = *(const float4*)&sB[kk][tx*4];
            fma44(a, b, acc);
        }
        __syncthreads();
    }
    float* dst = keyval + (size_t)z * 131072;
#pragma unroll
    for (int i = 0; i < 4; ++i)
#pragma unroll
        for (int j = 0; j < 4; ++j) {
            int col = j0 + tx*4 + j;
            dst[(size_t)(i0 + ty*4 + i)*256 + col] = acc[i][j] + b2[z*512 + col] + b2[z*512 + 256 + col];
        }
}

__global__ void k_fuse_transp(
    const float* __restrict__ part, const float* __restrict__ As,
    const float* __restrict__ Ps, ushortT* __restrict__ Gt)
{
    __shared__ float tile[32][33];
    int bx = blockIdx.x * 32, by = blockIdx.y * 32;
    int x = threadIdx.x, y0 = threadIdx.y;
    for (int yy = y0; yy < 32; yy += 8) {
        size_t id = (size_t)(by + yy)*kN + bx + x;
        float s = part[id] + part[262144 + id];
        float a = sigm(s);
        tile[yy][x] = a*As[id] + (1.f - a)*Ps[id];
    }
    __syncthreads();
    for (int yy = y0; yy < 32; yy += 8) Gt[(size_t)(bx+yy)*kN + by + x] = f2bf(tile[x][yy]);
}

__global__ __launch_bounds__(256) void k_cheby64(
    const ushortT* __restrict__ Gst, ushortT* __restrict__ Gst2)
{
    __shared__ short sA[64][40];
    __shared__ short sB[64][40];
    int tid = threadIdx.x;
    int m0 = blockIdx.y * 64, j0 = blockIdx.x * 64;
    int w = tid >> 6, lane = tid & 63;
    f32x4 acc[4];
#pragma unroll
    for (int i = 0; i < 4; ++i) acc[i] = (f32x4){0.f, 0.f, 0.f, 0.f};
    for (int k0 = 0; k0 < kN; k0 += 32) {
        {
            int row = tid >> 2, lc = (tid & 3) * 8;
            *(short8*)&sA[row][lc] = *(const short8*)(Gst + (size_t)(m0 + row)*kN + k0 + lc);
        }
        {
            int kr = tid & 31, jc = (tid >> 5) * 8;
            short8 v = *(const short8*)(Gst + (size_t)(k0 + kr)*kN + j0 + jc);
#pragma unroll
            for (int i = 0; i < 8; ++i) sB[jc + i][kr] = v[i];
        }
        __syncthreads();
        short8 bf = *(const short8*)&sB[w*16 + (lane & 15)][(lane >> 4) * 8];
#pragma unroll
        for (int mi = 0; mi < 4; ++mi) {
            short8 af = *(const short8*)&sA[mi*16 + (lane & 15)][(lane >> 4) * 8];
            acc[mi] = __builtin_amdgcn_mfma_f32_16x16x32_bf16(af, bf, acc[mi], 0, 0, 0);
        }
        __syncthreads();
    }
#pragma unroll
    for (int mi = 0; mi < 4; ++mi) {
        int row0 = m0 + mi*16 + (lane >> 4)*4;
        int col = j0 + w*16 + (lane & 15);
#pragma unroll
        for (int q = 0; q < 4; ++q) {
            int row = row0 + q;
            Gst2[(size_t)row*kN + col] = f2bf(2.f*acc[mi][q] - (row == col ? 1.f : 0.f));
        }
    }
}

// ---------------- mapped t1 (compile-time map) ----------------
template<int CLP, int PL, int ACTW, int OFF>
__global__ __launch_bounds__(256) void k_t1m(
    const ushortT* __restrict__ Gst, const ushortT* __restrict__ Xin, ushortT* __restrict__ Yout)
{
    __shared__ short sA[128][40];
    __shared__ short sB[128][40];
    int tid = threadIdx.x;
    int ki = blockIdx.z >> 2, b = blockIdx.z & 3;
    const ushortT* A = Gst + (size_t)ki * kN * kN;
    const ushortT* B = Xin + (size_t)b * kN * CLP;
    ushortT* C = Yout + (size_t)(ki*4 + b) * kN * CLP;
    int m0 = blockIdx.y * 128, j0 = blockIdx.x * 128;
    int w = tid >> 6, lane = tid & 63, wr = w >> 1, wc = w & 1;
    int kr = tid & 31, jc = (tid >> 5) * 8;
    int colr0, colr1;
    { int j = j0 + jc;      int cg = j / ACTW; colr0 = cg*PL + OFF + (j - cg*ACTW); }
    { int j = j0 + jc + 64; int cg = j / ACTW; colr1 = cg*PL + OFF + (j - cg*ACTW); }
    f32x4 acc[4][4];
#pragma unroll
    for (int i = 0; i < 4; ++i)
#pragma unroll
        for (int j = 0; j < 4; ++j) acc[i][j] = (f32x4){0.f, 0.f, 0.f, 0.f};

    for (int k0 = 0; k0 < kN; k0 += 32) {
        {
            int row = tid >> 1, lc = (tid & 1) * 16;
            const ushortT* p = A + (size_t)(m0 + row)*kN + k0 + lc;
            *(short8*)&sA[row][lc]     = *(const short8*)p;
            *(short8*)&sA[row][lc + 8] = *(const short8*)(p + 8);
        }
        {
            short8 v0 = *(const short8*)(B + (size_t)(k0 + kr)*CLP + colr0);
            short8 v1 = *(const short8*)(B + (size_t)(k0 + kr)*CLP + colr1);
#pragma unroll
            for (int i = 0; i < 8; ++i) sB[jc + i][kr] = v0[i];
#pragma unroll
            for (int i = 0; i < 8; ++i) sB[jc + 64 + i][kr] = v1[i];
        }
        __syncthreads();
        short8 af[4], bfr[4];
#pragma unroll
        for (int mi = 0; mi < 4; ++mi)
            af[mi] = *(const short8*)&sA[wr*64 + mi*16 + (lane & 15)][(lane >> 4) * 8];
#pragma unroll
        for (int ni = 0; ni < 4; ++ni)
            bfr[ni] = *(const short8*)&sB[wc*64 + ni*16 + (lane & 15)][(lane >> 4) * 8];
#pragma unroll
        for (int mi = 0; mi < 4; ++mi)
#pragma unroll
            for (int ni = 0; ni < 4; ++ni)
                acc[mi][ni] = __builtin_amdgcn_mfma_f32_16x16x32_bf16(af[mi], bfr[ni], acc[mi][ni], 0, 0, 0);
        __syncthreads();
    }
#pragma unroll
    for (int mi = 0; mi < 4; ++mi) {
#pragma unroll
        for (int ni = 0; ni < 4; ++ni) {
            int row = m0 + wr*64 + mi*16 + (lane >> 4) * 4;
            int fj = j0 + wc*64 + ni*16;
            int cg = fj / ACTW;
            int col = cg*PL + OFF + (fj - cg*ACTW) + (lane & 15);
#pragma unroll
            for (int q = 0; q < 4; ++q)
                C[(size_t)(row + q)*CLP + col] = f2bf(acc[mi][ni][q]);
        }
    }
}

// dec gates t1 with optional feat block (blockIdx.x == 4)
__global__ __launch_bounds__(256) void k_t1m_decg(
    const ushortT* __restrict__ Gst, const ushortT* __restrict__ Xin, ushortT* __restrict__ Yout)
{
    constexpr int CLP = 1280, PL = 160;
    __shared__ short sA[128][40];
    __shared__ short sB[128][40];
    int tid = threadIdx.x;
    int ki = blockIdx.z >> 2, b = blockIdx.z & 3;
    const ushortT* A = Gst + (size_t)ki * kN * kN;
    const ushortT* B = Xin + (size_t)b * kN * CLP;
    ushortT* C = Yout + (size_t)(ki*4 + b) * kN * CLP;
    int ACTW, OFF, j0;
    if (blockIdx.x < 4) { ACTW = 64; OFF = 0; j0 = blockIdx.x * 128; }
    else                { ACTW = 16; OFF = 128; j0 = 0; }
    int m0 = blockIdx.y * 128;
    int w = tid >> 6, lane = tid & 63, wr = w >> 1, wc = w & 1;
    int kr = tid & 31, jc = (tid >> 5) * 8;
    int colr0, colr1;
    { int j = j0 + jc;      int cg = j / ACTW; colr0 = cg*PL + OFF + (j - cg*ACTW); }
    { int j = j0 + jc + 64; int cg = j / ACTW; colr1 = cg*PL + OFF + (j - cg*ACTW); }
    f32x4 acc[4][4];
#pragma unroll
    for (int i = 0; i < 4; ++i)
#pragma unroll
        for (int j = 0; j < 4; ++j) acc[i][j] = (f32x4){0.f, 0.f, 0.f, 0.f};

    for (int k0 = 0; k0 < kN; k0 += 32) {
        {
            int row = tid >> 1, lc = (tid & 1) * 16;
            const ushortT* p = A + (size_t)(m0 + row)*kN + k0 + lc;
            *(short8*)&sA[row][lc]     = *(const short8*)p;
            *(short8*)&sA[row][lc + 8] = *(const short8*)(p + 8);
        }
        {
            short8 v0 = *(const short8*)(B + (size_t)(k0 + kr)*CLP + colr0);
            short8 v1 = *(const short8*)(B + (size_t)(k0 + kr)*CLP + colr1);
#pragma unroll
            for (int i = 0; i < 8; ++i) sB[jc + i][kr] = v0[i];
#pragma unroll
            for (int i = 0; i < 8; ++i) sB[jc + 64 + i][kr] = v1[i];
        }
        __syncthreads();
        short8 af[4], bfr[4];
#pragma unroll
        for (int mi = 0; mi < 4; ++mi)
            af[mi] = *(const short8*)&sA[wr*64 + mi*16 + (lane & 15)][(lane >> 4) * 8];
#pragma unroll
        for (int ni = 0; ni < 4; ++ni)
            bfr[ni] = *(const short8*)&sB[wc*64 + ni*16 + (lane & 15)][(lane >> 4) * 8];
#pragma unroll
        for (int mi = 0; mi < 4; ++mi)
#pragma unroll
            for (int ni = 0; ni < 4; ++ni)
                acc[mi][ni] = __builtin_amdgcn_mfma_f32_16x16x32_bf16(af[mi], bfr[ni], acc[mi][ni], 0, 0, 0);
        __syncthreads();
    }
#pragma unroll
    for (int mi = 0; mi < 4; ++mi) {
#pragma unroll
        for (int ni = 0; ni < 4; ++ni) {
            int row = m0 + wr*64 + mi*16 + (lane >> 4) * 4;
            int fj = j0 + wc*64 + ni*16;
            int cg = fj / ACTW;
            int col = cg*PL + OFF + (fj - cg*ACTW) + (lane & 15);
#pragma unroll
            for (int q = 0; q < 4; ++q)
                C[(size_t)(row + q)*CLP + col] = f2bf(acc[mi][ni][q]);
        }
    }
}

// ---------------- gathered-K GEMM (gates/cand) ----------------
template<int PL, int NQ, int MODE, int FN>
__global__ __launch_bounds__(256) void k_gg(
    const ushortT* __restrict__ XH, const ushortT* __restrict__ Yb,
    const ushortT* __restrict__ WT, float* __restrict__ Cout)
{
    constexpr int BN = 32 * FN;
    constexpr int KP = NQ * 32;
    constexpr int Ntot = 64 * FN;
    __shared__ short sA[128][40];
    __shared__ short sB[BN][40];
    int tid = threadIdx.x;
    int r0 = blockIdx.y * 128, j0 = blockIdx.x * BN;
    int b = r0 >> 12, rr = r0 & 4095;
    const ushortT* src0 = XH + (size_t)r0 * PL;
    const ushortT* src1 = Yb + ((size_t)b       * 4096 + rr) * PL;
    const ushortT* src2 = Yb + ((size_t)(4 + b) * 4096 + rr) * PL;
    int w = tid >> 6, lane = tid & 63, wr = w >> 1, wc = w & 1;
    f32x4 acc[4][FN];
#pragma unroll
    for (int i = 0; i < 4; ++i)
#pragma unroll
        for (int j = 0; j < FN; ++j) acc[i][j] = (f32x4){0.f, 0.f, 0.f, 0.f};

    for (int q = 0; q < NQ; ++q) {
        int k, off;
        if (MODE == 0)      { k = q/3; off = (q - k*3)*32; }
        else if (MODE == 1) { k = q/3; int part = q - k*3; off = (part < 2) ? part*32 : 128; }
        else                { k = q/5; off = (q - k*5)*32; }
        const ushortT* Ap = (k == 0) ? src0 : (k == 1) ? src1 : src2;
        {
            int row = tid >> 1, lc = (tid & 1) * 16;
            const ushortT* p = Ap + (size_t)row * PL + off + lc;
            *(short8*)&sA[row][lc]     = *(const short8*)p;
            *(short8*)&sA[row][lc + 8] = *(const short8*)(p + 8);
        }
        if (FN == 4) {
            int col = tid >> 1, seg = (tid & 1) * 16;
            const ushortT* p = WT + (size_t)(j0 + col)*KP + q*32 + seg;
            *(short8*)&sB[col][seg]     = *(const short8*)p;
            *(short8*)&sB[col][seg + 8] = *(const short8*)(p + 8);
        } else {
            int col = tid >> 2, seg = (tid & 3) * 8;
            *(short8*)&sB[col][seg] = *(const short8*)(WT + (size_t)(j0 + col)*KP + q*32 + seg);
        }
        __syncthreads();
        short8 af[4], bfr[FN];
#pragma unroll
        for (int mi = 0; mi < 4; ++mi)
            af[mi] = *(const short8*)&sA[wr*64 + mi*16 + (lane & 15)][(lane >> 4) * 8];
#pragma unroll
        for (int ni = 0; ni < FN; ++ni)
            bfr[ni] = *(const short8*)&sB[wc*16*FN + ni*16 + (lane & 15)][(lane >> 4) * 8];
#pragma unroll
        for (int mi = 0; mi < 4; ++mi)
#pragma unroll
            for (int ni = 0; ni < FN; ++ni)
                acc[mi][ni] = __builtin_amdgcn_mfma_f32_16x16x32_bf16(af[mi], bfr[ni], acc[mi][ni], 0, 0, 0);
        __syncthreads();
    }
#pragma unroll
    for (int mi = 0; mi < 4; ++mi) {
#pragma unroll
        for (int ni = 0; ni < FN; ++ni) {
            int row = r0 + wr*64 + mi*16 + (lane >> 4) * 4;
            int col = j0 + wc*16*FN + ni*16 + (lane & 15);
#pragma unroll
            for (int q = 0; q < 4; ++q)
                Cout[(size_t)(row + q)*Ntot + col] = acc[mi][ni][q];
        }
    }
}

// ---------------- epilogues ----------------

template<int PL, int XOFF>
__global__ __launch_bounds__(256) void k_gates_ep(
    const float* __restrict__ Gg, const float* __restrict__ GcM,
    const float* __restrict__ gb, const float* __restrict__ Ht,
    float* __restrict__ upd, ushortT* __restrict__ XH)
{
    __shared__ float sG[8][256];
    __shared__ float GcS[64];
    int tid = threadIdx.x, bm = blockIdx.x;
    const float* src = Gg + (size_t)bm * 2048;
    for (int i = tid; i < 2048; i += 256) sG[i >> 8][i & 255] = src[i];
    if (tid < 64) GcS[tid] = GcM[tid];
    __syncthreads();
    int d = tid >> 5, o0 = (tid & 31) * 4;
    size_t rb = (size_t)bm * 8 + d;
#pragma unroll
    for (int q = 0; q < 4; ++q) {
        int o = o0 + q;
        float pre = sG[d][o] + gb[o];
#pragma unroll
        for (int c = 0; c < 8; ++c) pre += GcS[c*8 + d] * sG[c][128 + o];
        float g = sigm(pre);
        if (o < kH) upd[rb*kH + o] = g;
        else {
            int h = o - kH;
            XH[rb*PL + XOFF + h] = f2bf(g * Ht[rb*kH + h]);
        }
    }
}

template<int MODE>
__global__ __launch_bounds__(256) void k_cand_ep(
    const float* __restrict__ Gc2, const float* __restrict__ GcM,
    const float* __restrict__ cb, const float* __restrict__ upd,
    float* __restrict__ Ht, ushortT* __restrict__ XHo,
    const float* __restrict__ X, int tnext,
    const float* __restrict__ ow1, const float* __restrict__ ob1,
    const float* __restrict__ ow2, const float* __restrict__ ob2,
    float* __restrict__ out, int hz)
{
    __shared__ float sG[8][128];
    __shared__ float GcS[64];
    __shared__ float Hn[8][65];
    __shared__ float Pp[8][32];
    int tid = threadIdx.x, bm = blockIdx.x;
    const float* src = Gc2 + (size_t)bm * 1024;
    for (int i = tid; i < 1024; i += 256) sG[i >> 7][i & 127] = src[i];
    if (tid < 64) GcS[tid] = GcM[tid];
    __syncthreads();
    int d = tid >> 5, o0 = (tid & 31) * 2;
    size_t rb = (size_t)bm * 8 + d;
#pragma unroll
    for (int jj = 0; jj < 2; ++jj) {
        int o = o0 + jj;
        float pre = sG[d][o] + cb[o];
#pragma unroll
        for (int c = 0; c < 8; ++c) pre += GcS[c*8 + d] * sG[c][64 + o];
        float cv = tanhf(pre);
        float u = upd[rb*kH + o];
        float h0 = Ht[rb*kH + o];
        float hn = (1.f - u)*h0 + u*cv;
        Ht[rb*kH + o] = hn;
        if (MODE >= 2) Hn[d][o] = hn;
        if (MODE == 0)      XHo[rb*PL_ENC + o] = f2bf(hn);
        else if (MODE <= 2) XHo[rb*PL_DEC + o] = f2bf(hn);
    }
    if (MODE == 0) {
        if (tid < 8) {
            int r = bm*8 + tid;
            int c2 = r & 7, m = (r >> 3) & 511, b2 = r >> 12;
            XHo[(size_t)r*PL_ENC + 64] = f2bf(X[(((size_t)b2*kT + tnext)*kN + m)*kC + c2]);
        }
    }
    if (MODE >= 2) {
        __syncthreads();
        int row = tid >> 5, e = tid & 31;
        float s = ob1[e];
#pragma unroll
        for (int k = 0; k < kH; ++k) s += Hn[row][k] * ow1[k*kE + e];
        Pp[row][e] = fmaxf(s, 0.f) * ow2[e];
        __syncthreads();
        if (tid < 8) {
            float v = ob2[0];
#pragma unroll
            for (int e2 = 0; e2 < 32; ++e2) v += Pp[tid][e2];
            int r = bm*8 + tid;
            int c2 = r & 7, m = (r >> 3) & 511, b2 = r >> 12;
            out[((size_t)(b2*kHOR + hz)*kN + m)*kC + c2] = v;
        }
    }
}

// ---------------- host ----------------
extern "C" void kernel_launch(void* const* d_in, const int* in_sizes, int n_in,
                              void* d_out, int out_size, void* d_ws, size_t ws_size,
                              hipStream_t stream)
{
    (void)in_sizes; (void)n_in; (void)out_size; (void)ws_size;
    const float* X      = (const float*)d_in[0];
    const float* As     = (const float*)d_in[1];
    const float* Ac     = (const float*)d_in[2];
    const float* featr  = (const float*)d_in[3];
    const float* WuS    = (const float*)d_in[4];
    const float* WvS    = (const float*)d_in[5];
    const float* WuC    = (const float*)d_in[6];
    const float* WvC    = (const float*)d_in[7];
    const float* mfS_w1 = (const float*)d_in[8];
    const float* mfS_b1 = (const float*)d_in[9];
    const float* mfS_w2 = (const float*)d_in[10];
    const float* mfS_b2 = (const float*)d_in[11];
    const float* mfC_w1 = (const float*)d_in[12];
    const float* mfC_b1 = (const float*)d_in[13];
    const float* mfC_w2 = (const float*)d_in[14];
    const float* mfC_b2 = (const float*)d_in[15];
    const float* enc_gW = (const float*)d_in[16];
    const float* enc_gb = (const float*)d_in[17];
    const float* enc_cW = (const float*)d_in[18];
    const float* enc_cb = (const float*)d_in[19];
    const float* dec_gW = (const float*)d_in[20];
    const float* dec_gb = (const float*)d_in[21];
    const float* dec_cW = (const float*)d_in[22];
    const float* dec_cb = (const float*)d_in[23];
    const float* out_w1 = (const float*)d_in[24];
    const float* out_b1 = (const float*)d_in[25];
    const float* out_w2 = (const float*)d_in[26];
    const float* out_b2 = (const float*)d_in[27];
    float* out = (float*)d_out;
    float* ws = (float*)d_ws;

    // ---- arena (floats) ----
    float* Ht     = ws;                      // 1,048,576
    float* updb   = Ht + 1048576;            // 1,048,576
    float* Gg     = updb + 1048576;          // 4,194,304 (GEMM out + phase1 aliases)
    float* Gs_pad = Gg + 4194304;            // 262,144 (phase1: Uc/Vc)
    float* smallf = Gs_pad + 262144;         // 8,192
    float* nfS = smallf;
    float* AnS = nfS + 1024;
    float* PnS = AnS + 1024;
    float* GcF = PnS + 1024;
    float* kvC = GcF + 64;                   // 4096
    ushortT* XHb  = (ushortT*)(smallf + 8192);   // enc XH: 16384*96
    ushortT* Yb   = XHb + 2621440;               // 5,242,880
    ushortT* GstB = Yb + 5242880;                // 524,288 (Gst + Gst2)
    ushortT* WTg_e = GstB + 524288;              // 73,728
    ushortT* WTc_e = WTg_e + 73728;              // 36,864
    ushortT* WTg_d = WTc_e + 36864;              // 73,728 used
    ushortT* WTc_d = WTg_d + 122880;             // 61,440
    ushortT* XHd   = WTc_d + 61440;              // 16384*160
    // phase-1 aliases inside Gg
    float* Upr   = Gg;                       // 786,432
    float* Vpr   = Upr + 786432;             // 786,432
    float* part  = Vpr + 786432;             // 1,048,576 (4 slices)
    float* Ps    = part + 1048576;           // 262,144
    float* hidKV = Ps + 262144;              // 524,288 (hidK | hidV)
    float* keyval= hidKV + 524288;           // 262,144 (keyS | valS)
    float* w2tKV = keyval + 262144;          // 262,144
    float* Uc    = Gs_pad;                   // 12,288 (phase-1 only)
    float* Vc    = Uc + 12288;               // 12,288

    constexpr int CLP_ENC = kC * PL_ENC;   // 768
    constexpr int CLP_DEC = kC * PL_DEC;   // 1280

    // ---- phase 0: all independent front work in one launch ----
    k_front<<<17368, 256, 0, stream>>>(
        enc_gW, enc_cW, dec_gW, dec_cW, mfS_w2,
        X, WuS, WvS, As, WuC, WvC, featr,
        WTg_e, WTc_e, WTg_d, WTc_d, w2tKV, w2tKV + 131072,
        Upr, Vpr, nfS, Uc, Vc, XHb, XHd, Ht);

    // ---- phase 1 ----
    k_p2<<<272, 256, 0, stream>>>(Upr, Vpr, part, Uc, Vc, Ac,
                                  mfC_w1, mfC_b1, mfC_w2, mfC_b2, kvC);
    k_p3<<<513, 256, 0, stream>>>(part, As, nfS, Ps, AnS, PnS, kvC, Uc, Vc, Ac, GcF);
    k_mlp1kv<<<2048, 256, 0, stream>>>(AnS, PnS, mfS_w1, mfS_b1, hidKV);
    k_ntsk_kv2<<<dim3(4, 8, 2), 256, 0, stream>>>(hidKV, w2tKV, mfS_b2, keyval);
    k_gemm_ntsk<<<dim3(8, 8, 2), 256, 0, stream>>>(keyval, keyval + 131072, part, 512, 512, 256, 128);
    k_fuse_transp<<<dim3(16, 16), dim3(32, 8), 0, stream>>>(part, As, Ps, GstB);
    k_cheby64<<<dim3(8, 8), 256, 0, stream>>>(GstB, GstB + 262144);

    // ---- encoder ----
    for (int t = 0; t < kT; ++t) {
        if (t == 0)
            k_t1m<CLP_ENC, PL_ENC, 96, 0><<<dim3(6, 4, 8), 256, 0, stream>>>(GstB, XHb, Yb);
        else
            k_t1m<CLP_ENC, PL_ENC, 80, 0><<<dim3(5, 4, 8), 256, 0, stream>>>(GstB, XHb, Yb);
        k_gg<PL_ENC, 9, 0, 4><<<dim3(2, 128), 256, 0, stream>>>(XHb, Yb, WTg_e, Gg);
        k_gates_ep<PL_ENC, 0><<<2048, 256, 0, stream>>>(Gg, GcF, enc_gb, Ht, updb, XHb);
        k_t1m<CLP_ENC, PL_ENC, 64, 0><<<dim3(4, 4, 8), 256, 0, stream>>>(GstB, XHb, Yb);
        k_gg<PL_ENC, 9, 0, 2><<<dim3(2, 128), 256, 0, stream>>>(XHb, Yb, WTc_e, Gg);
        if (t < kT - 1)
            k_cand_ep<0><<<2048, 256, 0, stream>>>(Gg, GcF, enc_cb, updb, Ht, XHb, X, t + 1,
                                                   nullptr, nullptr, nullptr, nullptr, nullptr, 0);
        else
            k_cand_ep<1><<<2048, 256, 0, stream>>>(Gg, GcF, enc_cb, updb, Ht, XHd, nullptr, 0,
                                                   nullptr, nullptr, nullptr, nullptr, nullptr, 0);
    }

    // ---- decoder ----
    for (int hz = 0; hz < kHOR; ++hz) {
        if (hz == 0)
            k_t1m_decg<<<dim3(5, 4, 8), 256, 0, stream>>>(GstB, XHd, Yb);  // gates t1 + feat-Y
        else
            k_t1m_decg<<<dim3(4, 4, 8), 256, 0, stream>>>(GstB, XHd, Yb);
        k_gg<PL_DEC, 9, 1, 4><<<dim3(2, 128), 256, 0, stream>>>(XHd, Yb, WTg_d, Gg);
        k_gates_ep<PL_DEC, 64><<<2048, 256, 0, stream>>>(Gg, GcF, dec_gb, Ht, updb, XHd);
        k_t1m<CLP_DEC, PL_DEC, 64, 64><<<dim3(4, 4, 8), 256, 0, stream>>>(GstB, XHd, Yb);
        k_gg<PL_DEC, 15, 2, 2><<<dim3(2, 128), 256, 0, stream>>>(XHd, Yb, WTc_d, Gg);
        if (hz < kHOR - 1)
            k_cand_ep<2><<<2048, 256, 0, stream>>>(Gg, GcF, dec_cb, updb, Ht, XHd, nullptr, 0,
                                                   out_w1, out_b1, out_w2, out_b2, out, hz);
        else
            k_cand_ep<3><<<2048, 256, 0, stream>>>(Gg, GcF, dec_cb, updb, Ht, XHd, nullptr, 0,
                                                   out_w1, out_b1, out_w2, out_b2, out, hz);
    }
}

// Round 18
// 878.326 us; speedup vs baseline: 1.0220x; 1.0017x over previous
//
#include <hip/hip_runtime.h>
#include <math.h>

// ---------------- problem constants ----------------
constexpr int kB = 4, kT = 6, kN = 512, kC = 8;
constexpr int kH = 64, kF = 16, kE = 32;
constexpr int kKS = 3, kKC = 2, kHOR = 3;
constexpr int kBT = kB * kT;          // 24
constexpr int kRK = kBT * kH;         // 1536
constexpr int L_ENC = 1 + kH + kF;    // 81
constexpr int L_DEC = kH + kH + kF;   // 144
constexpr int PL_ENC = 96;            // enc XH: [Ht(0:64)|Xt(64)|pad(65:80)|feat(80:96)]
constexpr int PL_DEC = 160;           // dec XH: [Hd(0:64)|rHd(64:128)|feat(128:144)|pad]
constexpr int KP_ENC = 3 * PL_ENC;    // 288
constexpr int KP_DGF = 288;           // dec gates folded
constexpr int KP_DEC = 3 * PL_DEC;    // 480 (dec cand)
constexpr float kALPHA = 3.0f;

typedef unsigned short ushortT;
typedef short short8 __attribute__((ext_vector_type(8)));
typedef float f32x4 __attribute__((ext_vector_type(4)));

__device__ __forceinline__ float sigm(float x) { return 1.0f / (1.0f + __expf(-x)); }

__device__ __forceinline__ ushortT f2bf(float f) {
    union { float f; unsigned int u; } v; v.f = f;
    unsigned int r = v.u + 0x7fffu + ((v.u >> 16) & 1u);
    return (ushortT)(r >> 16);
}

__device__ __forceinline__ void fma44(const float4& a, const float4& b, float acc[4][4]) {
    acc[0][0] += a.x*b.x; acc[0][1] += a.x*b.y; acc[0][2] += a.x*b.z; acc[0][3] += a.x*b.w;
    acc[1][0] += a.y*b.x; acc[1][1] += a.y*b.y; acc[1][2] += a.y*b.z; acc[1][3] += a.y*b.w;
    acc[2][0] += a.z*b.x; acc[2][1] += a.z*b.y; acc[2][2] += a.z*b.z; acc[2][3] += a.z*b.w;
    acc[3][0] += a.w*b.x; acc[3][1] += a.w*b.y; acc[3][2] += a.w*b.z; acc[3][3] += a.w*b.w;
}

// ---------------- k_front: prep_all + uvproj_s/nfa + uvproj_c + build_init ----------------
__global__ __launch_bounds__(256) void k_front(
    const float* __restrict__ egW, const float* __restrict__ ecW,
    const float* __restrict__ dgW, const float* __restrict__ dcW,
    const float* __restrict__ w2,
    const float* __restrict__ X, const float* __restrict__ Wu, const float* __restrict__ Wv,
    const float* __restrict__ As, const float* __restrict__ WuC, const float* __restrict__ WvC,
    const float* __restrict__ featr,
    ushortT* __restrict__ WTg_e, ushortT* __restrict__ WTc_e,
    ushortT* __restrict__ WTg_d, ushortT* __restrict__ WTc_d,
    float* __restrict__ w2tK, float* __restrict__ w2tV,
    float* __restrict__ Upr, float* __restrict__ Vpr, float* __restrict__ nf,
    float* __restrict__ Uc, float* __restrict__ Vc,
    ushortT* __restrict__ XHe, ushortT* __restrict__ XHd, float* __restrict__ Ht)
{
    __shared__ float shmem[12288];
    int blk = blockIdx.x, tid = threadIdx.x;
    if (blk < 1472) {
        int idx = blk * 256 + tid;
        if (idx < 73728) {
            int qp = idx % KP_ENC, o = idx / KP_ENC;
            int kk = qp / PL_ENC, l = qp - kk * PL_ENC;
            int lo = (l < 64) ? l + 1 : (l == 64) ? 0 : (l < 80) ? L_ENC : (l - 15);
            int j = o / 128, oo = o - j * 128;
            float v = (lo < L_ENC) ? egW[(size_t)((kk*2 + j)*L_ENC + lo) * 128 + oo] : 0.f;
            WTg_e[idx] = f2bf(v);
        } else if (idx < 110592) {
            int r = idx - 73728;
            int qp = r % KP_ENC, o = r / KP_ENC;
            int kk = qp / PL_ENC, l = qp - kk * PL_ENC;
            int lo = (l < 64) ? l + 1 : (l == 64) ? 0 : (l < 80) ? L_ENC : (l - 15);
            int j = o / 64, oo = o - j * 64;
            float v = (lo < L_ENC) ? ecW[(size_t)((kk*2 + j)*L_ENC + lo) * 64 + oo] : 0.f;
            WTc_e[r] = f2bf(v);
        } else if (idx < 184320) {
            int r = idx - 110592;
            int qp = r % KP_DGF, o = r / KP_DGF;
            int k = qp / 96, p = qp - k * 96;
            int j = o >> 7, oo = o & 127;
            int base = (k*2 + j) * L_DEC;
            float v;
            if (p < 64)      v = dgW[(size_t)(base + p)*128 + oo] + dgW[(size_t)(base + 64 + p)*128 + oo];
            else if (p < 80) v = dgW[(size_t)(base + 128 + (p - 64))*128 + oo];
            else             v = 0.f;
            WTg_d[r] = f2bf(v);
        } else if (idx < 245760) {
            int r = idx - 184320;
            int qp = r % KP_DEC, o = r / KP_DEC;
            int kk = qp / PL_DEC, l = qp - kk * PL_DEC;
            int j = o / 64, oo = o - j * 64;
            float v = (l < L_DEC) ? dcW[(size_t)((kk*2 + j)*L_DEC + l) * 64 + oo] : 0.f;
            WTc_d[r] = f2bf(v);
        } else if (idx < 376832) {
            int r = idx - 245760;
            int kk = r & 511, n = r >> 9;
            int j = kk >> 8, k = kk & 255;
            w2tK[r] = w2[(size_t)(0 + j)*65536 + k*256 + n];
            w2tV[r] = w2[(size_t)(2 + j)*65536 + k*256 + n];
        }
    } else if (blk < 5056) {
        int b2 = blk - 1472;
        if (b2 >= 3072) {
            int i = b2 - 3072;
            float* sa = shmem;
            float a = 0.f;
            for (int j = tid; j < kN; j += 256) a += As[(size_t)i*kN + j];
            sa[tid] = a; __syncthreads();
            for (int s = 128; s > 0; s >>= 1) { if (tid < s) sa[tid] += sa[tid+s]; __syncthreads(); }
            if (!tid) { nf[i*2] = sa[0]; nf[i*2+1] = 1.0f; }
            return;
        }
        int idx = b2 * 256 + tid;
        int h = idx % kH; int bt = (idx / kH) % kBT; int n = idx / (kH * kBT);
        const float* xr = X + ((size_t)bt * kN + n) * kC;
        float u = 0.f, v = 0.f;
#pragma unroll
        for (int c = 0; c < kC; ++c) { float x = xr[c]; u += x * Wu[c*kH + h]; v += x * Wv[c*kH + h]; }
        Upr[(size_t)n * kRK + bt * kH + h] = tanhf(kALPHA * u);
        Vpr[(size_t)n * kRK + bt * kH + h] = tanhf(kALPHA * v);
    } else if (blk < 5080) {
        // uvproj_c with LDS-staged weights
        int bt = blk - 5056;
        float* Xs  = shmem;          // 4096
        float* Wus = shmem + 4096;   // 4096
        float* Wvs = shmem + 8192;   // 4096
        for (int i = tid; i < 4096; i += 256) Xs[i] = X[(size_t)bt*4096 + i];
        int c = tid >> 6, h = tid & 63;
        float u0 = 0.f, v0 = 0.f, u1 = 0.f, v1 = 0.f;
        for (int n0 = 0; n0 < 512; n0 += 64) {
            __syncthreads();
            for (int i = tid; i < 4096; i += 256) { Wus[i] = WuC[n0*64 + i]; Wvs[i] = WvC[n0*64 + i]; }
            __syncthreads();
#pragma unroll 8
            for (int nn = 0; nn < 64; ++nn) {
                float wu = Wus[nn*64 + h], wv = Wvs[nn*64 + h];
                float x0 = Xs[(n0+nn)*8 + c], x1 = Xs[(n0+nn)*8 + c + 4];
                u0 += x0*wu; v0 += x0*wv; u1 += x1*wu; v1 += x1*wv;
            }
        }
        Uc[(size_t)bt*512 + c*64 + h]       = tanhf(kALPHA * u0);
        Vc[(size_t)bt*512 + c*64 + h]       = tanhf(kALPHA * v0);
        Uc[(size_t)bt*512 + (c+4)*64 + h]   = tanhf(kALPHA * u1);
        Vc[(size_t)bt*512 + (c+4)*64 + h]   = tanhf(kALPHA * v1);
    } else {
        int idx = (blk - 5080) * 256 + tid;
        if (idx < 1572864) {
            int l = idx % PL_ENC; int r = idx / PL_ENC;
            float v;
            if (l < 64)       v = 0.f;
            else if (l == 64) { int c = r & 7, m = (r >> 3) & 511, b = r >> 12; v = X[(((size_t)b*kT)*kN + m)*kC + c]; }
            else if (l < 80)  v = 0.f;
            else              { int m = (r >> 3) & 511; v = featr[m*kF + (l - 80)]; }
            XHe[idx] = f2bf(v);
        } else if (idx < 2097152) {
            int r2 = idx - 1572864;
            int l2 = r2 & 31; int r = r2 >> 5;
            float v = (l2 < 16) ? featr[((r >> 3) & 511)*kF + l2] : 0.f;
            XHd[(size_t)r*PL_DEC + 128 + l2] = f2bf(v);
        } else if (idx < 3145728) {
            Ht[idx - 2097152] = 0.f;
        }
    }
}

// ---------------- categorical front helper (bank-conflict-padded LDS) ----------------
__device__ __forceinline__ void cat_front2(
    const float* __restrict__ Uc, const float* __restrict__ Vc, const float* __restrict__ Ac,
    float* UVs, float* red, float* McS, float* Pcs, float* rsA, float* Ans, float* Pns)
{
    int tid = threadIdx.x;
    int cd = tid >> 2, kc = tid & 3;
    int c = cd >> 3, d = cd & 7;
    float s = 0.f;
    for (int bt0 = 0; bt0 < kBT; bt0 += 4) {
        __syncthreads();
        for (int i = tid; i < 2048; i += 256) {
            int btL = i >> 9, rest = i & 511;
            int cc = rest >> 6, hh2 = rest & 63;
            int pidx = btL*520 + cc*65 + hh2;
            UVs[pidx]        = Uc[(size_t)bt0*512 + i];
            UVs[2080 + pidx] = Vc[(size_t)bt0*512 + i];
        }
        __syncthreads();
#pragma unroll
        for (int bt = 0; bt < 4; ++bt)
#pragma unroll
            for (int hh = 0; hh < 16; ++hh) {
                int h = kc*16 + hh;
                s += UVs[bt*520 + c*65 + h] * UVs[2080 + bt*520 + d*65 + h];
            }
    }
    red[tid] = s; __syncthreads();
    if (tid < 64) McS[tid] = red[tid*4] + red[tid*4+1] + red[tid*4+2] + red[tid*4+3];
    __syncthreads();
    if (tid < 8) {
        int i = tid;
        float row[8]; float mx = -1e30f;
#pragma unroll
        for (int j = 0; j < 8; ++j) { float v = fmaxf(McS[i*8+j] - McS[j*8+i], 0.f); row[j] = v; mx = fmaxf(mx, v); }
        float s2 = 0.f;
#pragma unroll
        for (int j = 0; j < 8; ++j) { row[j] = __expf(row[j] - mx); s2 += row[j]; }
        float inv = 1.f / s2;
#pragma unroll
        for (int j = 0; j < 8; ++j) Pcs[i*8+j] = row[j] * inv;
        float a = 0.f;
#pragma unroll
        for (int j = 0; j < 8; ++j) a += Ac[i*8+j];
        rsA[i] = a;
    }
    __syncthreads();
    if (tid < 16) {
        int i = tid >> 1, comp = tid & 1;
        float an = 0.f, pn = 0.f;
#pragma unroll
        for (int j = 0; j < 8; ++j) {
            float nfj = comp ? 1.f : rsA[j];
            an += Ac[i*8+j] * nfj; pn += Pcs[i*8+j] * nfj;
        }
        Ans[i*2+comp] = an; Pns[i*2+comp] = pn;
    }
    __syncthreads();
}

// ---------------- k_p2: Ms split-K4 GEMM (256 blocks) + catmlp (16 blocks) ----------------
union P2Smem {
    struct { float sA[32][68]; float sB[32][68]; } g;
    struct { float UVs[4160]; float red[256]; float McS[64]; float Pcs[64]; float rsA[8];
             float Ans[16]; float Pns[16]; float hA[8][260]; float hP[8][260]; } c;
};

__global__ __launch_bounds__(256) void k_p2(
    const float* __restrict__ Upr, const float* __restrict__ Vpr, float* __restrict__ part,
    const float* __restrict__ Uc, const float* __restrict__ Vc, const float* __restrict__ Ac,
    const float* __restrict__ w1, const float* __restrict__ b1,
    const float* __restrict__ w2C, const float* __restrict__ b2c,
    float* __restrict__ keyval)
{
    __shared__ P2Smem sm;
    int tid = threadIdx.x;
    if (blockIdx.x < 256) {
        int x = blockIdx.x & 7, y = (blockIdx.x >> 3) & 7, z = blockIdx.x >> 6;
        int tx = tid & 15, ty = tid >> 4;
        int j0 = x * 64, i0 = y * 64;
        int kb = z * 384;
        float acc[4][4] = {};
        for (int k0 = kb; k0 < kb + 384; k0 += 32) {
#pragma unroll
            for (int it = 0; it < 2; ++it) {
                int q = tid + it * 256;
                int row = q >> 3, ks = (q & 7) * 4;
                float4 va = *(const float4*)&Upr[(size_t)(i0 + row)*1536 + k0 + ks];
                float4 vb = *(const float4*)&Vpr[(size_t)(j0 + row)*1536 + k0 + ks];
                sm.g.sA[ks+0][row] = va.x; sm.g.sA[ks+1][row] = va.y; sm.g.sA[ks+2][row] = va.z; sm.g.sA[ks+3][row] = va.w;
                sm.g.sB[ks+0][row] = vb.x; sm.g.sB[ks+1][row] = vb.y; sm.g.sB[ks+2][row] = vb.z; sm.g.sB[ks+3][row] = vb.w;
            }
            __syncthreads();
#pragma unroll
            for (int kk = 0; kk < 32; ++kk) {
                float4 a = *(const float4*)&sm.g.sA[kk][ty*4];
                float4 b = *(const float4*)&sm.g.sB[kk][tx*4];
                fma44(a, b, acc);
            }
            __syncthreads();
        }
        float* dst = part + (size_t)z * 262144;
#pragma unroll
        for (int i = 0; i < 4; ++i)
#pragma unroll
            for (int j = 0; j < 4; ++j)
                dst[(size_t)(i0 + ty*4 + i)*512 + j0 + tx*4 + j] = acc[i][j];
    } else {
        int r = blockIdx.x - 256;
        int kv = r & 1, c0 = (r >> 1) * 32;
        int qa = kv*2, qp = kv*2 + 1;
        cat_front2(Uc, Vc, Ac, sm.c.UVs, sm.c.red, sm.c.McS, sm.c.Pcs, sm.c.rsA, sm.c.Ans, sm.c.Pns);
        for (int e = tid; e < 2048; e += 256) {
            int i = e >> 8, o = e & 255;
            sm.c.hA[i][o] = fmaxf(sm.c.Ans[i*2]*w1[qa*512 + o] + sm.c.Ans[i*2+1]*w1[qa*512 + 256 + o] + b1[qa*256 + o], 0.f);
            sm.c.hP[i][o] = fmaxf(sm.c.Pns[i*2]*w1[qp*512 + o] + sm.c.Pns[i*2+1]*w1[qp*512 + 256 + o] + b1[qp*256 + o], 0.f);
        }
        __syncthreads();
        int i = tid >> 5, ocl = tid & 31, oc = c0 + ocl;
        float s = b2c[qa*256 + oc] + b2c[qp*256 + oc];
        const float* wA = w2C + (size_t)qa*65536 + oc;
        const float* wP = w2C + (size_t)qp*65536 + oc;
#pragma unroll 4
        for (int k = 0; k < 256; ++k) {
            s += sm.c.hA[i][k] * wA[(size_t)k*256] + sm.c.hP[i][k] * wP[(size_t)k*256];
        }
        keyval[(size_t)kv*2048 + i*256 + oc] = s;
    }
}

// ---------------- k_p3: softmax/anpn (512 blocks) + gcfuse (1 block) ----------------
union P3Smem {
    struct { float s0[256]; float s1[256]; float s2[256]; float s3[256]; float s4[256]; } s;
    struct { float UVs[4160]; float red[256]; float McS[64]; float Pcs[64]; float rsA[8];
             float Ans[16]; float Pns[16]; float dotp[256]; } c;
};

__global__ __launch_bounds__(256) void k_p3(
    const float* __restrict__ part, const float* __restrict__ A, const float* __restrict__ nf,
    float* __restrict__ P, float* __restrict__ An, float* __restrict__ Pn,
    const float* __restrict__ keyval,
    const float* __restrict__ Uc, const float* __restrict__ Vc, const float* __restrict__ Ac,
    float* __restrict__ GcF)
{
    __shared__ P3Smem sm;
    int tid = threadIdx.x;
    if (blockIdx.x < 512) {
        int i = blockIdx.x;
        auto mval = [&](int r, int c2) -> float {
            size_t id = (size_t)r*kN + c2;
            return part[id] + part[262144 + id] + part[524288 + id] + part[786432 + id];
        };
        float mx = -1e30f;
        for (int j = tid; j < kN; j += 256)
            mx = fmaxf(mx, fmaxf(mval(i, j) - mval(j, i), 0.f));
        sm.s.s0[tid] = mx; __syncthreads();
        for (int s = 128; s > 0; s >>= 1) { if (tid < s) sm.s.s0[tid] = fmaxf(sm.s.s0[tid], sm.s.s0[tid+s]); __syncthreads(); }
        mx = sm.s.s0[0]; __syncthreads();
        float sum=0, pn0=0, pn1=0, an0=0, an1=0;
        for (int j = tid; j < kN; j += 256) {
            float v = fmaxf(mval(i, j) - mval(j, i), 0.f);
            float e = __expf(v - mx);
            P[(size_t)i*kN + j] = e;
            float n0 = nf[2*j], n1 = nf[2*j+1];
            float a = A[(size_t)i*kN + j];
            sum += e; pn0 += e*n0; pn1 += e*n1; an0 += a*n0; an1 += a*n1;
        }
        sm.s.s0[tid]=sum; sm.s.s1[tid]=pn0; sm.s.s2[tid]=pn1; sm.s.s3[tid]=an0; sm.s.s4[tid]=an1; __syncthreads();
        for (int s = 128; s > 0; s >>= 1) {
            if (tid < s) { sm.s.s0[tid]+=sm.s.s0[tid+s]; sm.s.s1[tid]+=sm.s.s1[tid+s]; sm.s.s2[tid]+=sm.s.s2[tid+s]; sm.s.s3[tid]+=sm.s.s3[tid+s]; sm.s.s4[tid]+=sm.s.s4[tid+s]; }
            __syncthreads();
        }
        float inv = 1.f / sm.s.s0[0];
        if (!tid) { Pn[i*2] = sm.s.s1[0]*inv; Pn[i*2+1] = sm.s.s2[0]*inv; An[i*2] = sm.s.s3[0]; An[i*2+1] = sm.s.s4[0]; }
        __syncthreads();
        for (int j = tid; j < kN; j += 256) P[(size_t)i*kN + j] *= inv;
    } else {
        cat_front2(Uc, Vc, Ac, sm.c.UVs, sm.c.red, sm.c.McS, sm.c.Pcs, sm.c.rsA, sm.c.Ans, sm.c.Pns);
        int cd = tid >> 2, kc = tid & 3;
        int c = cd >> 3, d = cd & 7;
        const float* key = keyval;
        const float* val = keyval + 2048;
        float s = 0.f;
#pragma unroll 4
        for (int k = kc*64; k < kc*64 + 64; k += 4) {
            float4 k4 = *(const float4*)&key[c*256 + k];
            float4 v4 = *(const float4*)&val[d*256 + k];
            s += k4.x*v4.x + k4.y*v4.y + k4.z*v4.z + k4.w*v4.w;
        }
        sm.c.dotp[tid] = s; __syncthreads();
        if (tid < 64) {
            float t = sm.c.dotp[tid*4] + sm.c.dotp[tid*4+1] + sm.c.dotp[tid*4+2] + sm.c.dotp[tid*4+3];
            float a = sigm(t);
            GcF[tid] = a*Ac[tid] + (1.f - a)*sm.c.Pcs[tid];
        }
    }
}

// ---------------- remaining spatial-chain kernels ----------------

__global__ __launch_bounds__(256) void k_mlp1kv(
    const float* __restrict__ An, const float* __restrict__ Pn,
    const float* __restrict__ w1, const float* __restrict__ b1, float* __restrict__ hid)
{
    int idx = blockIdx.x * 256 + threadIdx.x;
    if (idx >= 524288) return;
    int half = idx >> 18;
    int r = idx & 262143;
    int col = r & 511, i = r >> 9;
    int ia = half*2, ip = half*2 + 1;
    float v;
    if (col < 256) {
        const float* w = w1 + (size_t)ia * 512;
        v = An[i*2]*w[col] + An[i*2+1]*w[256 + col] + b1[ia*256 + col];
    } else {
        int o = col - 256;
        const float* w = w1 + (size_t)ip * 512;
        v = Pn[i*2]*w[o] + Pn[i*2+1]*w[256 + o] + b1[ip*256 + o];
    }
    hid[idx] = fmaxf(v, 0.f);
}

__global__ __launch_bounds__(256) void k_gemm_ntsk(
    const float* __restrict__ A, const float* __restrict__ B, float* __restrict__ part,
    int M, int N, int K, int skl)
{
    __shared__ __align__(16) float sA[32][68];
    __shared__ __align__(16) float sB[32][68];
    int tid = threadIdx.x, tx = tid & 15, ty = tid >> 4;
    int j0 = blockIdx.x * 64, i0 = blockIdx.y * 64;
    int kb = blockIdx.z * skl;
    float acc[4][4] = {};
    for (int k0 = kb; k0 < kb + skl; k0 += 32) {
#pragma unroll
        for (int it = 0; it < 2; ++it) {
            int q = tid + it * 256;
            int row = q >> 3, ks = (q & 7) * 4;
            float4 va = *(const float4*)&A[(size_t)(i0 + row)*K + k0 + ks];
            float4 vb = *(const float4*)&B[(size_t)(j0 + row)*K + k0 + ks];
            sA[ks+0][row] = va.x; sA[ks+1][row] = va.y; sA[ks+2][row] = va.z; sA[ks+3][row] = va.w;
            sB[ks+0][row] = vb.x; sB[ks+1][row] = vb.y; sB[ks+2][row] = vb.z; sB[ks+3][row] = vb.w;
        }
        __syncthreads();
#pragma unroll
        for (int kk = 0; kk < 32; ++kk) {
            float4 a = *(const float4*)&sA[kk][ty*4];
            float4 b = *(const float4*)&sB[kk][tx*4];
            fma44(a, b, acc);
        }
        __syncthreads();
    }
    float* dst = part + (size_t)blockIdx.z * M * N;
#pragma unroll
    for (int i = 0; i < 4; ++i)
#pragma unroll
        for (int j = 0; j < 4; ++j)
            dst[(size_t)(i0 + ty*4 + i)*N + j0 + tx*4 + j] = acc[i][j];
}

__global__ __launch_bounds__(256) void k_ntsk_kv2(
    const float* __restrict__ hid, const float* __restrict__ w2t,
    const float* __restrict__ b2, float* __restrict__ keyval)
{
    __shared__ __align__(16) float sA[32][68];
    __shared__ __align__(16) float sB[32][68];
    int tid = threadIdx.x, tx = tid & 15, ty = tid >> 4;
    int z = blockIdx.z;
    const float* A = hid + (size_t)z * 262144;
    const float* B = w2t + (size_t)z * 131072;
    int j0 = blockIdx.x * 64, i0 = blockIdx.y * 64;
    float acc[4][4] = {};
    for (int k0 = 0; k0 < 512; k0 += 32) {
#pragma unroll
        for (int it = 0; it < 2; ++it) {
            int q = tid + it * 256;
            int row = q >> 3, ks = (q & 7) * 4;
            float4 va = *(const float4*)&A[(size_t)(i0 + row)*512 + k0 + ks];
            float4 vb = *(const float4*)&B[(size_t)(j0 + row)*512 + k0 + ks];
            sA[ks+0][row] = va.x; sA[ks+1][row] = va.y; sA[ks+2][row] = va.z; sA[ks+3][row] = va.w;
            sB[ks+0][row] = vb.x; sB[ks+1][row] = vb.y; sB[ks+2][row] = vb.z; sB[ks+3][row] = vb.w;
        }
        __syncthreads();
#pragma unroll
        for (int kk = 0; kk < 32; ++kk) {
            float4 a = *(const float4*)&sA[kk][ty*4];
            float4 b = *(const float4*)&sB[kk][tx*4];
            fma44(a, b, acc);
        }
        __syncthreads();
    }
    float* dst = keyval + (size_t)z * 131072;
#pragma unroll
    for (int i = 0; i < 4; ++i)
#pragma unroll
        for (int j = 0; j < 4; ++j) {
            int col = j0 + tx*4 + j;
            dst[(size_t)(i0 + ty*4 + i)*256 + col] = acc[i][j] + b2[z*512 + col] + b2[z*512 + 256 + col];
        }
}

__global__ void k_fuse_transp(
    const float* __restrict__ part, const float* __restrict__ As,
    const float* __restrict__ Ps, ushortT* __restrict__ Gt)
{
    __shared__ float tile[32][33];
    int bx = blockIdx.x * 32, by = blockIdx.y * 32;
    int x = threadIdx.x, y0 = threadIdx.y;
    for (int yy = y0; yy < 32; yy += 8) {
        size_t id = (size_t)(by + yy)*kN + bx + x;
        float s = part[id] + part[262144 + id];
        float a = sigm(s);
        tile[yy][x] = a*As[id] + (1.f - a)*Ps[id];
    }
    __syncthreads();
    for (int yy = y0; yy < 32; yy += 8) Gt[(size_t)(bx+yy)*kN + by + x] = f2bf(tile[x][yy]);
}

__global__ __launch_bounds__(256) void k_cheby64(
    const ushortT* __restrict__ Gst, ushortT* __restrict__ Gst2)
{
    __shared__ short sA[64][40];
    __shared__ short sB[64][40];
    int tid = threadIdx.x;
    int m0 = blockIdx.y * 64, j0 = blockIdx.x * 64;
    int w = tid >> 6, lane = tid & 63;
    f32x4 acc[4];
#pragma unroll
    for (int i = 0; i < 4; ++i) acc[i] = (f32x4){0.f, 0.f, 0.f, 0.f};
    for (int k0 = 0; k0 < kN; k0 += 32) {
        {
            int row = tid >> 2, lc = (tid & 3) * 8;
            *(short8*)&sA[row][lc] = *(const short8*)(Gst + (size_t)(m0 + row)*kN + k0 + lc);
        }
        {
            int kr = tid & 31, jc = (tid >> 5) * 8;
            short8 v = *(const short8*)(Gst + (size_t)(k0 + kr)*kN + j0 + jc);
#pragma unroll
            for (int i = 0; i < 8; ++i) sB[jc + i][kr] = v[i];
        }
        __syncthreads();
        short8 bf = *(const short8*)&sB[w*16 + (lane & 15)][(lane >> 4) * 8];
#pragma unroll
        for (int mi = 0; mi < 4; ++mi) {
            short8 af = *(const short8*)&sA[mi*16 + (lane & 15)][(lane >> 4) * 8];
            acc[mi] = __builtin_amdgcn_mfma_f32_16x16x32_bf16(af, bf, acc[mi], 0, 0, 0);
        }
        __syncthreads();
    }
#pragma unroll
    for (int mi = 0; mi < 4; ++mi) {
        int row0 = m0 + mi*16 + (lane >> 4)*4;
        int col = j0 + w*16 + (lane & 15);
#pragma unroll
        for (int q = 0; q < 4; ++q) {
            int row = row0 + q;
            Gst2[(size_t)row*kN + col] = f2bf(2.f*acc[mi][q] - (row == col ? 1.f : 0.f));
        }
    }
}

// ---------------- mapped t1 (compile-time map) ----------------
template<int CLP, int PL, int ACTW, int OFF>
__global__ __launch_bounds__(256) void k_t1m(
    const ushortT* __restrict__ Gst, const ushortT* __restrict__ Xin, ushortT* __restrict__ Yout)
{
    __shared__ short sA[128][40];
    __shared__ short sB[128][40];
    int tid = threadIdx.x;
    int ki = blockIdx.z >> 2, b = blockIdx.z & 3;
    const ushortT* A = Gst + (size_t)ki * kN * kN;
    const ushortT* B = Xin + (size_t)b * kN * CLP;
    ushortT* C = Yout + (size_t)(ki*4 + b) * kN * CLP;
    int m0 = blockIdx.y * 128, j0 = blockIdx.x * 128;
    int w = tid >> 6, lane = tid & 63, wr = w >> 1, wc = w & 1;
    int kr = tid & 31, jc = (tid >> 5) * 8;
    int colr0, colr1;
    { int j = j0 + jc;      int cg = j / ACTW; colr0 = cg*PL + OFF + (j - cg*ACTW); }
    { int j = j0 + jc + 64; int cg = j / ACTW; colr1 = cg*PL + OFF + (j - cg*ACTW); }
    f32x4 acc[4][4];
#pragma unroll
    for (int i = 0; i < 4; ++i)
#pragma unroll
        for (int j = 0; j < 4; ++j) acc[i][j] = (f32x4){0.f, 0.f, 0.f, 0.f};

    for (int k0 = 0; k0 < kN; k0 += 32) {
        {
            int row = tid >> 1, lc = (tid & 1) * 16;
            const ushortT* p = A + (size_t)(m0 + row)*kN + k0 + lc;
            *(short8*)&sA[row][lc]     = *(const short8*)p;
            *(short8*)&sA[row][lc + 8] = *(const short8*)(p + 8);
        }
        {
            short8 v0 = *(const short8*)(B + (size_t)(k0 + kr)*CLP + colr0);
            short8 v1 = *(const short8*)(B + (size_t)(k0 + kr)*CLP + colr1);
#pragma unroll
            for (int i = 0; i < 8; ++i) sB[jc + i][kr] = v0[i];
#pragma unroll
            for (int i = 0; i < 8; ++i) sB[jc + 64 + i][kr] = v1[i];
        }
        __syncthreads();
        short8 af[4], bfr[4];
#pragma unroll
        for (int mi = 0; mi < 4; ++mi)
            af[mi] = *(const short8*)&sA[wr*64 + mi*16 + (lane & 15)][(lane >> 4) * 8];
#pragma unroll
        for (int ni = 0; ni < 4; ++ni)
            bfr[ni] = *(const short8*)&sB[wc*64 + ni*16 + (lane & 15)][(lane >> 4) * 8];
#pragma unroll
        for (int mi = 0; mi < 4; ++mi)
#pragma unroll
            for (int ni = 0; ni < 4; ++ni)
                acc[mi][ni] = __builtin_amdgcn_mfma_f32_16x16x32_bf16(af[mi], bfr[ni], acc[mi][ni], 0, 0, 0);
        __syncthreads();
    }
#pragma unroll
    for (int mi = 0; mi < 4; ++mi) {
#pragma unroll
        for (int ni = 0; ni < 4; ++ni) {
            int row = m0 + wr*64 + mi*16 + (lane >> 4) * 4;
            int fj = j0 + wc*64 + ni*16;
            int cg = fj / ACTW;
            int col = cg*PL + OFF + (fj - cg*ACTW) + (lane & 15);
#pragma unroll
            for (int q = 0; q < 4; ++q)
                C[(size_t)(row + q)*CLP + col] = f2bf(acc[mi][ni][q]);
        }
    }
}

// dec gates t1 with optional feat block (blockIdx.x == 4)
__global__ __launch_bounds__(256) void k_t1m_decg(
    const ushortT* __restrict__ Gst, const ushortT* __restrict__ Xin, ushortT* __restrict__ Yout)
{
    constexpr int CLP = 1280, PL = 160;
    __shared__ short sA[128][40];
    __shared__ short sB[128][40];
    int tid = threadIdx.x;
    int ki = blockIdx.z >> 2, b = blockIdx.z & 3;
    const ushortT* A = Gst + (size_t)ki * kN * kN;
    const ushortT* B = Xin + (size_t)b * kN * CLP;
    ushortT* C = Yout + (size_t)(ki*4 + b) * kN * CLP;
    int ACTW, OFF, j0;
    if (blockIdx.x < 4) { ACTW = 64; OFF = 0; j0 = blockIdx.x * 128; }
    else                { ACTW = 16; OFF = 128; j0 = 0; }
    int m0 = blockIdx.y * 128;
    int w = tid >> 6, lane = tid & 63, wr = w >> 1, wc = w & 1;
    int kr = tid & 31, jc = (tid >> 5) * 8;
    int colr0, colr1;
    { int j = j0 + jc;      int cg = j / ACTW; colr0 = cg*PL + OFF + (j - cg*ACTW); }
    { int j = j0 + jc + 64; int cg = j / ACTW; colr1 = cg*PL + OFF + (j - cg*ACTW); }
    f32x4 acc[4][4];
#pragma unroll
    for (int i = 0; i < 4; ++i)
#pragma unroll
        for (int j = 0; j < 4; ++j) acc[i][j] = (f32x4){0.f, 0.f, 0.f, 0.f};

    for (int k0 = 0; k0 < kN; k0 += 32) {
        {
            int row = tid >> 1, lc = (tid & 1) * 16;
            const ushortT* p = A + (size_t)(m0 + row)*kN + k0 + lc;
            *(short8*)&sA[row][lc]     = *(const short8*)p;
            *(short8*)&sA[row][lc + 8] = *(const short8*)(p + 8);
        }
        {
            short8 v0 = *(const short8*)(B + (size_t)(k0 + kr)*CLP + colr0);
            short8 v1 = *(const short8*)(B + (size_t)(k0 + kr)*CLP + colr1);
#pragma unroll
            for (int i = 0; i < 8; ++i) sB[jc + i][kr] = v0[i];
#pragma unroll
            for (int i = 0; i < 8; ++i) sB[jc + 64 + i][kr] = v1[i];
        }
        __syncthreads();
        short8 af[4], bfr[4];
#pragma unroll
        for (int mi = 0; mi < 4; ++mi)
            af[mi] = *(const short8*)&sA[wr*64 + mi*16 + (lane & 15)][(lane >> 4) * 8];
#pragma unroll
        for (int ni = 0; ni < 4; ++ni)
            bfr[ni] = *(const short8*)&sB[wc*64 + ni*16 + (lane & 15)][(lane >> 4) * 8];
#pragma unroll
        for (int mi = 0; mi < 4; ++mi)
#pragma unroll
            for (int ni = 0; ni < 4; ++ni)
                acc[mi][ni] = __builtin_amdgcn_mfma_f32_16x16x32_bf16(af[mi], bfr[ni], acc[mi][ni], 0, 0, 0);
        __syncthreads();
    }
#pragma unroll
    for (int mi = 0; mi < 4; ++mi) {
#pragma unroll
        for (int ni = 0; ni < 4; ++ni) {
            int row = m0 + wr*64 + mi*16 + (lane >> 4) * 4;
            int fj = j0 + wc*64 + ni*16;
            int cg = fj / ACTW;
            int col = cg*PL + OFF + (fj - cg*ACTW) + (lane & 15);
#pragma unroll
            for (int q = 0; q < 4; ++q)
                C[(size_t)(row + q)*CLP + col] = f2bf(acc[mi][ni][q]);
        }
    }
}

// ---------------- gathered-K GEMM (gates/cand) ----------------
template<int PL, int NQ, int MODE, int FN>
__global__ __launch_bounds__(256) void k_gg(
    const ushortT* __restrict__ XH, const ushortT* __restrict__ Yb,
    const ushortT* __restrict__ WT, float* __restrict__ Cout)
{
    constexpr int BN = 32 * FN;
    constexpr int KP = NQ * 32;
    constexpr int Ntot = 64 * FN;
    __shared__ short sA[128][40];
    __shared__ short sB[BN][40];
    int tid = threadIdx.x;
    int r0 = blockIdx.y * 128, j0 = blockIdx.x * BN;
    int b = r0 >> 12, rr = r0 & 4095;
    const ushortT* src0 = XH + (size_t)r0 * PL;
    const ushortT* src1 = Yb + ((size_t)b       * 4096 + rr) * PL;
    const ushortT* src2 = Yb + ((size_t)(4 + b) * 4096 + rr) * PL;
    int w = tid >> 6, lane = tid & 63, wr = w >> 1, wc = w & 1;
    f32x4 acc[4][FN];
#pragma unroll
    for (int i = 0; i < 4; ++i)
#pragma unroll
        for (int j = 0; j < FN; ++j) acc[i][j] = (f32x4){0.f, 0.f, 0.f, 0.f};

    for (int q = 0; q < NQ; ++q) {
        int k, off;
        if (MODE == 0)      { k = q/3; off = (q - k*3)*32; }
        else if (MODE == 1) { k = q/3; int part = q - k*3; off = (part < 2) ? part*32 : 128; }
        else                { k = q/5; off = (q - k*5)*32; }
        const ushortT* Ap = (k == 0) ? src0 : (k == 1) ? src1 : src2;
        {
            int row = tid >> 1, lc = (tid & 1) * 16;
            const ushortT* p = Ap + (size_t)row * PL + off + lc;
            *(short8*)&sA[row][lc]     = *(const short8*)p;
            *(short8*)&sA[row][lc + 8] = *(const short8*)(p + 8);
        }
        if (FN == 4) {
            int col = tid >> 1, seg = (tid & 1) * 16;
            const ushortT* p = WT + (size_t)(j0 + col)*KP + q*32 + seg;
            *(short8*)&sB[col][seg]     = *(const short8*)p;
            *(short8*)&sB[col][seg + 8] = *(const short8*)(p + 8);
        } else {
            int col = tid >> 2, seg = (tid & 3) * 8;
            *(short8*)&sB[col][seg] = *(const short8*)(WT + (size_t)(j0 + col)*KP + q*32 + seg);
        }
        __syncthreads();
        short8 af[4], bfr[FN];
#pragma unroll
        for (int mi = 0; mi < 4; ++mi)
            af[mi] = *(const short8*)&sA[wr*64 + mi*16 + (lane & 15)][(lane >> 4) * 8];
#pragma unroll
        for (int ni = 0; ni < FN; ++ni)
            bfr[ni] = *(const short8*)&sB[wc*16*FN + ni*16 + (lane & 15)][(lane >> 4) * 8];
#pragma unroll
        for (int mi = 0; mi < 4; ++mi)
#pragma unroll
            for (int ni = 0; ni < FN; ++ni)
                acc[mi][ni] = __builtin_amdgcn_mfma_f32_16x16x32_bf16(af[mi], bfr[ni], acc[mi][ni], 0, 0, 0);
        __syncthreads();
    }
#pragma unroll
    for (int mi = 0; mi < 4; ++mi) {
#pragma unroll
        for (int ni = 0; ni < FN; ++ni) {
            int row = r0 + wr*64 + mi*16 + (lane >> 4) * 4;
            int col = j0 + wc*16*FN + ni*16 + (lane & 15);
#pragma unroll
            for (int q = 0; q < 4; ++q)
                Cout[(size_t)(row + q)*Ntot + col] = acc[mi][ni][q];
        }
    }
}

// ---------------- epilogues ----------------

template<int PL, int XOFF>
__global__ __launch_bounds__(256) void k_gates_ep(
    const float* __restrict__ Gg, const float* __restrict__ GcM,
    const float* __restrict__ gb, const float* __restrict__ Ht,
    float* __restrict__ upd, ushortT* __restrict__ XH)
{
    __shared__ float sG[8][256];
    __shared__ float GcS[64];
    int tid = threadIdx.x, bm = blockIdx.x;
    const float* src = Gg + (size_t)bm * 2048;
    for (int i = tid; i < 2048; i += 256) sG[i >> 8][i & 255] = src[i];
    if (tid < 64) GcS[tid] = GcM[tid];
    __syncthreads();
    int d = tid >> 5, o0 = (tid & 31) * 4;
    size_t rb = (size_t)bm * 8 + d;
#pragma unroll
    for (int q = 0; q < 4; ++q) {
        int o = o0 + q;
        float pre = sG[d][o] + gb[o];
#pragma unroll
        for (int c = 0; c < 8; ++c) pre += GcS[c*8 + d] * sG[c][128 + o];
        float g = sigm(pre);
        if (o < kH) upd[rb*kH + o] = g;
        else {
            int h = o - kH;
            XH[rb*PL + XOFF + h] = f2bf(g * Ht[rb*kH + h]);
        }
    }
}

template<int MODE>
__global__ __launch_bounds__(256) void k_cand_ep(
    const float* __restrict__ Gc2, const float* __restrict__ GcM,
    const float* __restrict__ cb, const float* __restrict__ upd,
    float* __restrict__ Ht, ushortT* __restrict__ XHo,
    const float* __restrict__ X, int tnext,
    const float* __restrict__ ow1, const float* __restrict__ ob1,
    const float* __restrict__ ow2, const float* __restrict__ ob2,
    float* __restrict__ out, int hz)
{
    __shared__ float sG[8][128];
    __shared__ float GcS[64];
    __shared__ float Hn[8][65];
    __shared__ float Pp[8][32];
    int tid = threadIdx.x, bm = blockIdx.x;
    const float* src = Gc2 + (size_t)bm * 1024;
    for (int i = tid; i < 1024; i += 256) sG[i >> 7][i & 127] = src[i];
    if (tid < 64) GcS[tid] = GcM[tid];
    __syncthreads();
    int d = tid >> 5, o0 = (tid & 31) * 2;
    size_t rb = (size_t)bm * 8 + d;
#pragma unroll
    for (int jj = 0; jj < 2; ++jj) {
        int o = o0 + jj;
        float pre = sG[d][o] + cb[o];
#pragma unroll
        for (int c = 0; c < 8; ++c) pre += GcS[c*8 + d] * sG[c][64 + o];
        float cv = tanhf(pre);
        float u = upd[rb*kH + o];
        float h0 = Ht[rb*kH + o];
        float hn = (1.f - u)*h0 + u*cv;
        Ht[rb*kH + o] = hn;
        if (MODE >= 2) Hn[d][o] = hn;
        if (MODE == 0)      XHo[rb*PL_ENC + o] = f2bf(hn);
        else if (MODE <= 2) XHo[rb*PL_DEC + o] = f2bf(hn);
    }
    if (MODE == 0) {
        if (tid < 8) {
            int r = bm*8 + tid;
            int c2 = r & 7, m = (r >> 3) & 511, b2 = r >> 12;
            XHo[(size_t)r*PL_ENC + 64] = f2bf(X[(((size_t)b2*kT + tnext)*kN + m)*kC + c2]);
        }
    }
    if (MODE >= 2) {
        __syncthreads();
        int row = tid >> 5, e = tid & 31;
        float s = ob1[e];
#pragma unroll
        for (int k = 0; k < kH; ++k) s += Hn[row][k] * ow1[k*kE + e];
        Pp[row][e] = fmaxf(s, 0.f) * ow2[e];
        __syncthreads();
        if (tid < 8) {
            float v = ob2[0];
#pragma unroll
            for (int e2 = 0; e2 < 32; ++e2) v += Pp[tid][e2];
            int r = bm*8 + tid;
            int c2 = r & 7, m = (r >> 3) & 511, b2 = r >> 12;
            out[((size_t)(b2*kHOR + hz)*kN + m)*kC + c2] = v;
        }
    }
}

// ---------------- host ----------------
extern "C" void kernel_launch(void* const* d_in, const int* in_sizes, int n_in,
                              void* d_out, int out_size, void* d_ws, size_t ws_size,
                              hipStream_t stream)
{
    (void)in_sizes; (void)n_in; (void)out_size; (void)ws_size;
    const float* X      = (const float*)d_in[0];
    const float* As     = (const float*)d_in[1];
    const float* Ac     = (const float*)d_in[2];
    const float* featr  = (const float*)d_in[3];
    const float* WuS    = (const float*)d_in[4];
    const float* WvS    = (const float*)d_in[5];
    const float* WuC    = (const float*)d_in[6];
    const float* WvC    = (const float*)d_in[7];
    const float* mfS_w1 = (const float*)d_in[8];
    const float* mfS_b1 = (const float*)d_in[9];
    const float* mfS_w2 = (const float*)d_in[10];
    const float* mfS_b2 = (const float*)d_in[11];
    const float* mfC_w1 = (const float*)d_in[12];
    const float* mfC_b1 = (const float*)d_in[13];
    const float* mfC_w2 = (const float*)d_in[14];
    const float* mfC_b2 = (const float*)d_in[15];
    const float* enc_gW = (const float*)d_in[16];
    const float* enc_gb = (const float*)d_in[17];
    const float* enc_cW = (const float*)d_in[18];
    const float* enc_cb = (const float*)d_in[19];
    const float* dec_gW = (const float*)d_in[20];
    const float* dec_gb = (const float*)d_in[21];
    const float* dec_cW = (const float*)d_in[22];
    const float* dec_cb = (const float*)d_in[23];
    const float* out_w1 = (const float*)d_in[24];
    const float* out_b1 = (const float*)d_in[25];
    const float* out_w2 = (const float*)d_in[26];
    const float* out_b2 = (const float*)d_in[27];
    float* out = (float*)d_out;
    float* ws = (float*)d_ws;

    // ---- arena (floats) ----
    float* Ht     = ws;                      // 1,048,576
    float* updb   = Ht + 1048576;            // 1,048,576
    float* Gg     = updb + 1048576;          // 4,194,304 (GEMM out + phase1 aliases)
    float* Gs_pad = Gg + 4194304;            // 262,144 (phase1: Uc/Vc)
    float* smallf = Gs_pad + 262144;         // 8,192
    float* nfS = smallf;
    float* AnS = nfS + 1024;
    float* PnS = AnS + 1024;
    float* GcF = PnS + 1024;
    float* kvC = GcF + 64;                   // 4096
    ushortT* XHb  = (ushortT*)(smallf + 8192);   // enc XH: 16384*96
    ushortT* Yb   = XHb + 2621440;               // 5,242,880
    ushortT* GstB = Yb + 5242880;                // 524,288 (Gst + Gst2)
    ushortT* WTg_e = GstB + 524288;              // 73,728
    ushortT* WTc_e = WTg_e + 73728;              // 36,864
    ushortT* WTg_d = WTc_e + 36864;              // 73,728 used
    ushortT* WTc_d = WTg_d + 122880;             // 61,440
    ushortT* XHd   = WTc_d + 61440;              // 16384*160
    // phase-1 aliases inside Gg
    float* Upr   = Gg;                       // 786,432
    float* Vpr   = Upr + 786432;             // 786,432
    float* part  = Vpr + 786432;             // 1,048,576 (4 slices)
    float* Ps    = part + 1048576;           // 262,144
    float* hidKV = Ps + 262144;              // 524,288 (hidK | hidV)
    float* keyval= hidKV + 524288;           // 262,144 (keyS | valS)
    float* w2tKV = keyval + 262144;          // 262,144
    float* Uc    = Gs_pad;                   // 12,288 (phase-1 only)
    float* Vc    = Uc + 12288;               // 12,288

    constexpr int CLP_ENC = kC * PL_ENC;   // 768
    constexpr int CLP_DEC = kC * PL_DEC;   // 1280

    // ---- phase 0: all independent front work in one launch ----
    k_front<<<17368, 256, 0, stream>>>(
        enc_gW, enc_cW, dec_gW, dec_cW, mfS_w2,
        X, WuS, WvS, As, WuC, WvC, featr,
        WTg_e, WTc_e, WTg_d, WTc_d, w2tKV, w2tKV + 131072,
        Upr, Vpr, nfS, Uc, Vc, XHb, XHd, Ht);

    // ---- phase 1 ----
    k_p2<<<272, 256, 0, stream>>>(Upr, Vpr, part, Uc, Vc, Ac,
                                  mfC_w1, mfC_b1, mfC_w2, mfC_b2, kvC);
    k_p3<<<513, 256, 0, stream>>>(part, As, nfS, Ps, AnS, PnS, kvC, Uc, Vc, Ac, GcF);
    k_mlp1kv<<<2048, 256, 0, stream>>>(AnS, PnS, mfS_w1, mfS_b1, hidKV);
    k_ntsk_kv2<<<dim3(4, 8, 2), 256, 0, stream>>>(hidKV, w2tKV, mfS_b2, keyval);
    k_gemm_ntsk<<<dim3(8, 8, 2), 256, 0, stream>>>(keyval, keyval + 131072, part, 512, 512, 256, 128);
    k_fuse_transp<<<dim3(16, 16), dim3(32, 8), 0, stream>>>(part, As, Ps, GstB);
    k_cheby64<<<dim3(8, 8), 256, 0, stream>>>(GstB, GstB + 262144);

    // ---- encoder ----
    for (int t = 0; t < kT; ++t) {
        if (t == 0)
            k_t1m<CLP_ENC, PL_ENC, 96, 0><<<dim3(6, 4, 8), 256, 0, stream>>>(GstB, XHb, Yb);
        else
            k_t1m<CLP_ENC, PL_ENC, 80, 0><<<dim3(5, 4, 8), 256, 0, stream>>>(GstB, XHb, Yb);
        k_gg<PL_ENC, 9, 0, 4><<<dim3(2, 128), 256, 0, stream>>>(XHb, Yb, WTg_e, Gg);
        k_gates_ep<PL_ENC, 0><<<2048, 256, 0, stream>>>(Gg, GcF, enc_gb, Ht, updb, XHb);
        k_t1m<CLP_ENC, PL_ENC, 64, 0><<<dim3(4, 4, 8), 256, 0, stream>>>(GstB, XHb, Yb);
        k_gg<PL_ENC, 9, 0, 2><<<dim3(2, 128), 256, 0, stream>>>(XHb, Yb, WTc_e, Gg);
        if (t < kT - 1)
            k_cand_ep<0><<<2048, 256, 0, stream>>>(Gg, GcF, enc_cb, updb, Ht, XHb, X, t + 1,
                                                   nullptr, nullptr, nullptr, nullptr, nullptr, 0);
        else
            k_cand_ep<1><<<2048, 256, 0, stream>>>(Gg, GcF, enc_cb, updb, Ht, XHd, nullptr, 0,
                                                   nullptr, nullptr, nullptr, nullptr, nullptr, 0);
    }

    // ---- decoder ----
    for (int hz = 0; hz < kHOR; ++hz) {
        if (hz == 0)
            k_t1m_decg<<<dim3(5, 4, 8), 256, 0, stream>>>(GstB, XHd, Yb);  // gates t1 + feat-Y
        else
            k_t1m_decg<<<dim3(4, 4, 8), 256, 0, stream>>>(GstB, XHd, Yb);
        k_gg<PL_DEC, 9, 1, 4><<<dim3(2, 128), 256, 0, stream>>>(XHd, Yb, WTg_d, Gg);
        k_gates_ep<PL_DEC, 64><<<2048, 256, 0, stream>>>(Gg, GcF, dec_gb, Ht, updb, XHd);
        k_t1m<CLP_DEC, PL_DEC, 64, 64><<<dim3(4, 4, 8), 256, 0, stream>>>(GstB, XHd, Yb);
        k_gg<PL_DEC, 15, 2, 2><<<dim3(2, 128), 256, 0, stream>>>(XHd, Yb, WTc_d, Gg);
        if (hz < kHOR - 1)
            k_cand_ep<2><<<2048, 256, 0, stream>>>(Gg, GcF, dec_cb, updb, Ht, XHd, nullptr, 0,
                                                   out_w1, out_b1, out_w2, out_b2, out, hz);
        else
            k_cand_ep<3><<<2048, 256, 0, stream>>>(Gg, GcF, dec_cb, updb, Ht, XHd, nullptr, 0,
                                                   out_w1, out_b1, out_w2, out_b2, out, hz);
    }
}